// Round 3
// baseline (699.790 us; speedup 1.0000x reference)
//
#include <hip/hip_runtime.h>
#include <hip/hip_bf16.h>
#include <stdint.h>

#define N_NODES 50000
#define N_EDGES 800000
#define E_TOT   (N_EDGES + N_NODES)

// canonical fp32 buffer segment offsets (element counts)
#define OFF_X    0
#define OFF_W1   800000
#define OFF_AS1  804096
#define OFF_AD1  804352
#define OFF_B1   804608
#define OFF_W2   804864
#define OFF_AS2  821248
#define OFF_AD2  821312
#define OFF_B2   821376
#define OFF_FCW  821440
#define OFF_FCB  821504
#define N_CANON  821505

typedef __hip_bfloat16 bf16;

__device__ __forceinline__ float b2f(bf16 v){ return (float)v; }
__device__ __forceinline__ int clampi(int v, int lo, int hi){ return v < lo ? lo : (v > hi ? hi : v); }
__device__ __forceinline__ uint16_t f2bfbits(float f){
  union { float f; uint32_t u; } c; c.f = f;
  uint32_t r = c.u + 0x7fff + ((c.u >> 16) & 1);   // round-to-nearest-even
  return (uint16_t)(r >> 16);
}

// ---------------- dtype probes ----------------
// flag[0]: edge_index is int64 (little-endian, values < 2^31 => odd int32 words all 0)
// flag[1]: float inputs are fp32 (reading fp32 memory as bf16 stream gives wild exponents)
__global__ void k_detect(const int* __restrict__ ei, const uint16_t* __restrict__ xu,
                         int* __restrict__ flag){
  if(blockIdx.x != 0 || threadIdx.x != 0) return;
  int or_odd = 0;
  for(int i = 0; i < 64; i++) or_odd |= ei[2*i + 1];
  for(int i = 0; i < 64; i++) or_odd |= ei[2*(400000 + i) + 1];
  flag[0] = (or_odd == 0) ? 1 : 0;
  int hits = 0;
  for(int i = 0; i < 4096; i++){
    int e = (xu[i] >> 7) & 0xFF;
    hits += (e >= 200);
  }
  flag[1] = (hits > 16) ? 1 : 0;
}

__device__ __forceinline__ int load_src(const int* ei, int i, int f){
  return f ? ei[2*(size_t)i] : ei[i];
}
__device__ __forceinline__ int load_dst(const int* ei, int i, int f){
  return f ? ei[2*((size_t)N_EDGES + i)] : ei[N_EDGES + i];
}

// ---------------- canonicalize float inputs to fp32 ----------------
__global__ void k_convert(const void* x, const void* W1, const void* as1w, const void* ad1w,
                          const void* b1, const void* W2, const void* as2w, const void* ad2w,
                          const void* b2, const void* fcw, const void* fcb,
                          float* __restrict__ canon, const int* __restrict__ flag){
  int i = blockIdx.x*256 + threadIdx.x;
  if(i >= N_CANON) return;
  const void* src; int off;
  if     (i < OFF_W1 ){ src = x;    off = i; }
  else if(i < OFF_AS1){ src = W1;   off = i - OFF_W1; }
  else if(i < OFF_AD1){ src = as1w; off = i - OFF_AS1; }
  else if(i < OFF_B1 ){ src = ad1w; off = i - OFF_AD1; }
  else if(i < OFF_W2 ){ src = b1;   off = i - OFF_B1; }
  else if(i < OFF_AS2){ src = W2;   off = i - OFF_W2; }
  else if(i < OFF_AD2){ src = as2w; off = i - OFF_AS2; }
  else if(i < OFF_B2 ){ src = ad2w; off = i - OFF_AD2; }
  else if(i < OFF_FCW){ src = b2;   off = i - OFF_B2; }
  else if(i < OFF_FCB){ src = fcw;  off = i - OFF_FCW; }
  else               { src = fcb;  off = 0; }
  float v = flag[1] ? ((const float*)src)[off] : b2f(((const bf16*)src)[off]);
  canon[i] = v;
}

// ---------------- CSR build ----------------

__global__ void k_init_deg(int* deg){
  int i = blockIdx.x*256 + threadIdx.x;
  if(i < N_NODES) deg[i] = 1;            // self-loop pre-counted
}

__global__ void k_hist(const int* __restrict__ ei, int* __restrict__ deg, const int* __restrict__ flag){
  int i = blockIdx.x*256 + threadIdx.x;
  if(i < N_EDGES){
    int d = clampi(load_dst(ei, i, flag[0]), 0, N_NODES-1);
    atomicAdd(&deg[d], 1);
  }
}

__global__ __launch_bounds__(1024) void k_scan(const int* deg, int* offsets, int* cursor){
  __shared__ int wsum[16];
  __shared__ int carry_s;
  const int tid = threadIdx.x, lane = tid & 63, wid = tid >> 6;
  if(tid == 0) carry_s = 0;
  __syncthreads();
  for(int base = 0; base < N_NODES; base += 4096){
    int i0 = base + tid*4;
    int v0 = (i0+0 < N_NODES) ? deg[i0+0] : 0;
    int v1 = (i0+1 < N_NODES) ? deg[i0+1] : 0;
    int v2 = (i0+2 < N_NODES) ? deg[i0+2] : 0;
    int v3 = (i0+3 < N_NODES) ? deg[i0+3] : 0;
    int s = v0+v1+v2+v3;
    int incl = s;
    #pragma unroll
    for(int off=1; off<64; off<<=1){
      int t = __shfl_up(incl, off, 64);
      if(lane >= off) incl += t;
    }
    if(lane == 63) wsum[wid] = incl;
    __syncthreads();
    int wexcl = 0, total = 0;
    #pragma unroll
    for(int w=0; w<16; w++){
      int ws_ = wsum[w];
      if(w < wid) wexcl += ws_;
      total += ws_;
    }
    int o = carry_s + wexcl + (incl - s);
    if(i0+0 < N_NODES){ offsets[i0+0]=o; cursor[i0+0]=o; } o += v0;
    if(i0+1 < N_NODES){ offsets[i0+1]=o; cursor[i0+1]=o; } o += v1;
    if(i0+2 < N_NODES){ offsets[i0+2]=o; cursor[i0+2]=o; } o += v2;
    if(i0+3 < N_NODES){ offsets[i0+3]=o; cursor[i0+3]=o; }
    __syncthreads();
    if(tid == 0) carry_s += total;
    __syncthreads();
  }
  if(tid == 0) offsets[N_NODES] = carry_s;   // == E_TOT
}

__global__ void k_scatter(const int* __restrict__ ei, int* __restrict__ cursor, int* __restrict__ csr,
                          const int* __restrict__ flag){
  int i = blockIdx.x*256 + threadIdx.x;
  if(i >= E_TOT) return;
  int s, d;
  if(i < N_EDGES){
    int f = flag[0];
    s = clampi(load_src(ei, i, f), 0, N_NODES-1);
    d = clampi(load_dst(ei, i, f), 0, N_NODES-1);
  } else {
    s = i - N_EDGES; d = s;
  }
  int pos = atomicAdd(&cursor[d], 1);
  pos = clampi(pos, 0, E_TOT-1);
  csr[pos] = s;
}

// ---------------- Layer 1: h1 = x @ W1^T (16 -> 256), fused alpha ----------------
// 16 nodes per block; thread j owns output channel j (wave == head).

__global__ __launch_bounds__(256) void k_gemm1(const float* __restrict__ canon,
                        bf16* __restrict__ h1, float* __restrict__ as1, float* __restrict__ ad1){
  __shared__ __align__(16) float xs[256];    // 16 nodes x 16 features
  const int tid = threadIdx.x, lane = tid & 63, h = tid >> 6;
  const int n0 = blockIdx.x * 16;

  float w1r[16];
  #pragma unroll
  for(int k=0;k<16;k++) w1r[k] = canon[OFF_W1 + tid*16 + k];
  float asr = canon[OFF_AS1 + tid];
  float adr = canon[OFF_AD1 + tid];

  xs[tid] = canon[OFF_X + n0*16 + tid];
  __syncthreads();

  for(int nd=0; nd<16; nd++){
    const float* xr = &xs[nd*16];
    float acc = 0.f;
    #pragma unroll
    for(int k=0;k<16;k++) acc += xr[k]*w1r[k];
    int n = n0 + nd;
    h1[(size_t)n*256 + tid] = __float2bfloat16(acc);
    float vs = acc*asr, vd = acc*adr;
    #pragma unroll
    for(int off=32; off; off>>=1){ vs += __shfl_xor(vs, off, 64); vd += __shfl_xor(vd, off, 64); }
    if(lane == 0){ as1[n*4 + h] = vs; ad1[n*4 + h] = vd; }
  }
}

// ---------------- Layer 1 aggregate: softmax + weighted sum + bias + ELU ----

__global__ __launch_bounds__(256) void k_agg1(const int* __restrict__ offsets, const int* __restrict__ csr,
                       const bf16* __restrict__ h1, const float* __restrict__ as1, const float* __restrict__ ad1,
                       const float* __restrict__ canon, bf16* __restrict__ h1o){
  const int n = blockIdx.x;
  const int t = threadIdx.x, h = t >> 6;
  const int beg = offsets[n], end = offsets[n+1];
  const float adn = ad1[n*4 + h];
  float acc = 0.f, den = 1e-16f;
  for(int i = beg; i < end; i++){
    int s = clampi(csr[i], 0, N_NODES-1);
    float e = as1[s*4 + h] + adn;
    e = (e > 0.f) ? e : 0.2f*e;
    e = fminf(fmaxf(e, -60.f), 60.f);
    float w = __expf(e);
    den += w;
    acc += w * b2f(h1[(size_t)s*256 + t]);
  }
  float o = acc/den + canon[OFF_B1 + t];
  o = (o > 0.f) ? o : expm1f(o);
  h1o[(size_t)n*256 + t] = __float2bfloat16(o);
}

// ---------------- Layer 2 GEMM: h2 = h1o @ W2^T (256 -> 64), fused alpha2 ----------

__device__ __forceinline__ float2 bf16x2_to_f2(uint32_t u){
  union { uint32_t i; float f; } a, b;
  a.i = u << 16; b.i = u & 0xffff0000u;
  return make_float2(a.f, b.f);
}

__global__ __launch_bounds__(256) void k_gemm2(const bf16* __restrict__ h1o, const float* __restrict__ canon,
                        bf16* __restrict__ h2, float* __restrict__ as2, float* __restrict__ ad2){
  __shared__ uint32_t W2p[128*64];              // [kp][j] : packed bf16 (k=2kp, 2kp+1) of W2[j][k]
  __shared__ __align__(16) float hbuf[4][256];
  const int tid = threadIdx.x, j = tid & 63, nd = tid >> 6;

  for(int idx = tid; idx < 128*64; idx += 256){
    int kp = idx >> 6, jj = idx & 63;
    uint32_t lo = f2bfbits(canon[OFF_W2 + jj*256 + 2*kp    ]);
    uint32_t hi = f2bfbits(canon[OFF_W2 + jj*256 + 2*kp + 1]);
    W2p[idx] = lo | (hi << 16);
  }
  float asj = canon[OFF_AS2 + j];
  float adj = canon[OFF_AD2 + j];
  __syncthreads();

  for(int g = blockIdx.x; g < N_NODES/4; g += gridDim.x){
    int n0 = g*4;
    for(int idx = tid; idx < 1024; idx += 256){
      int nn = idx >> 8, k = idx & 255;
      hbuf[nn][k] = b2f(h1o[(size_t)(n0+nn)*256 + k]);
    }
    __syncthreads();
    const float2* hp = (const float2*)hbuf[nd];
    float acc = 0.f;
    #pragma unroll 8
    for(int kp = 0; kp < 128; kp++){
      float2 w2 = bf16x2_to_f2(W2p[kp*64 + j]);
      float2 hv = hp[kp];
      acc += hv.x*w2.x + hv.y*w2.y;
    }
    int n = n0 + nd;
    h2[(size_t)n*64 + j] = __float2bfloat16(acc);
    float vs = acc*asj, vd = acc*adj;
    #pragma unroll
    for(int off=32; off; off>>=1){ vs += __shfl_xor(vs, off, 64); vd += __shfl_xor(vd, off, 64); }
    if(j == 0){ as2[n] = vs; ad2[n] = vd; }
    __syncthreads();
  }
}

// ---------------- Layer 2 aggregate + bias + ELU + FC(64->1) --------------------

__global__ __launch_bounds__(256) void k_agg2(const int* __restrict__ offsets, const int* __restrict__ csr,
                       const bf16* __restrict__ h2, const float* __restrict__ as2, const float* __restrict__ ad2,
                       const float* __restrict__ canon, void* __restrict__ outv, const int* __restrict__ flag){
  const int nd = threadIdx.x >> 6, c = threadIdx.x & 63;
  const int n = blockIdx.x*4 + nd;
  const int beg = offsets[n], end = offsets[n+1];
  const float adn = ad2[n];
  float acc = 0.f, den = 1e-16f;
  for(int i = beg; i < end; i++){
    int s = clampi(csr[i], 0, N_NODES-1);
    float e = as2[s] + adn;
    e = (e > 0.f) ? e : 0.2f*e;
    e = fminf(fmaxf(e, -60.f), 60.f);
    float w = __expf(e);
    den += w;
    acc += w * b2f(h2[(size_t)s*64 + c]);
  }
  float o = acc/den + canon[OFF_B2 + c];
  o = (o > 0.f) ? o : expm1f(o);
  float v = o * canon[OFF_FCW + c];
  #pragma unroll
  for(int off=32; off; off>>=1) v += __shfl_xor(v, off, 64);
  if(c == 0){
    float r = v + canon[OFF_FCB];
    if(flag[1]) ((float*)outv)[n] = r;
    else        ((bf16*)outv)[n] = __float2bfloat16(r);
  }
}

// ---------------- launch ----------------

extern "C" void kernel_launch(void* const* d_in, const int* in_sizes, int n_in,
                              void* d_out, int out_size, void* d_ws, size_t ws_size,
                              hipStream_t stream){
  (void)in_sizes; (void)n_in; (void)out_size;
  const int* ei = (const int*)d_in[1];

  char* w = (char*)d_ws;
  auto carve = [&](size_t bytes)->char*{ char* p = w; w += (bytes + 255) & ~(size_t)255; return p; };
  int*   deg     = (int*)  carve((size_t)N_NODES*4);
  int*   offsets = (int*)  carve((size_t)(N_NODES+1)*4);
  int*   cursor  = (int*)  carve((size_t)N_NODES*4);
  int*   flag    = (int*)  carve(256);
  int*   csr     = (int*)  carve((size_t)E_TOT*4);
  float* canon   = (float*)carve((size_t)N_CANON*4);
  float* as1     = (float*)carve((size_t)N_NODES*4*4);
  float* ad1     = (float*)carve((size_t)N_NODES*4*4);
  float* as2     = (float*)carve((size_t)N_NODES*4);
  float* ad2     = (float*)carve((size_t)N_NODES*4);
  bf16*  h1      = (bf16*) carve((size_t)N_NODES*256*2);
  bf16*  h1o     = (bf16*) carve((size_t)N_NODES*256*2);
  bf16*  h2      = h1;                         // alias: h1 dead after k_agg1
  size_t required = (size_t)(w - (char*)d_ws);
  if(ws_size < required) return;               // diagnostic: output stays 0 => finite absmax

  hipLaunchKernelGGL(k_detect,   dim3(1), dim3(64), 0, stream, ei, (const uint16_t*)d_in[0], flag);
  hipLaunchKernelGGL(k_convert,  dim3((N_CANON+255)/256), dim3(256), 0, stream,
                     d_in[0], d_in[2], d_in[3], d_in[4], d_in[5], d_in[6], d_in[7], d_in[8],
                     d_in[9], d_in[10], d_in[11], canon, flag);
  hipLaunchKernelGGL(k_init_deg, dim3((N_NODES+255)/256), dim3(256), 0, stream, deg);
  hipLaunchKernelGGL(k_hist,     dim3((N_EDGES+255)/256), dim3(256), 0, stream, ei, deg, flag);
  hipLaunchKernelGGL(k_scan,     dim3(1), dim3(1024), 0, stream, deg, offsets, cursor);
  hipLaunchKernelGGL(k_scatter,  dim3((E_TOT+255)/256), dim3(256), 0, stream, ei, cursor, csr, flag);
  hipLaunchKernelGGL(k_gemm1,    dim3(N_NODES/16), dim3(256), 0, stream, canon, h1, as1, ad1);
  hipLaunchKernelGGL(k_agg1,     dim3(N_NODES), dim3(256), 0, stream, offsets, csr, h1, as1, ad1, canon, h1o);
  hipLaunchKernelGGL(k_gemm2,    dim3(1024), dim3(256), 0, stream, h1o, canon, h2, as2, ad2);
  hipLaunchKernelGGL(k_agg2,     dim3(N_NODES/4), dim3(256), 0, stream, offsets, csr, h2, as2, ad2, canon, d_out, flag);
}

// Round 4
// 490.184 us; speedup vs baseline: 1.4276x; 1.4276x over previous
//
#include <hip/hip_runtime.h>
#include <hip/hip_bf16.h>
#include <stdint.h>

#define N_NODES 50000
#define N_EDGES 800000
#define E_TOT   (N_EDGES + N_NODES)

// canonical fp32 buffer segment offsets (element counts)
#define OFF_X    0
#define OFF_W1   800000
#define OFF_AS1  804096
#define OFF_AD1  804352
#define OFF_B1   804608
#define OFF_W2   804864
#define OFF_AS2  821248
#define OFF_AD2  821312
#define OFF_B2   821376
#define OFF_FCW  821440
#define OFF_FCB  821504
#define N_CANON  821505

typedef __hip_bfloat16 bf16;

__device__ __forceinline__ float b2f(bf16 v){ return (float)v; }
__device__ __forceinline__ int clampi(int v, int lo, int hi){ return v < lo ? lo : (v > hi ? hi : v); }
__device__ __forceinline__ uint16_t f2bfbits(float f){
  union { float f; uint32_t u; } c; c.f = f;
  uint32_t r = c.u + 0x7fff + ((c.u >> 16) & 1);   // round-to-nearest-even
  return (uint16_t)(r >> 16);
}
__device__ __forceinline__ float bitsf(uint32_t u){
  union { uint32_t u; float f; } c; c.u = u; return c.f;
}

// ---------------- dtype probes (wave-parallel) ----------------
// flag[0]: edge_index is int64 (LE, values < 2^31 => odd int32 words all 0)
// flag[1]: float inputs are fp32 (fp32 memory read as bf16 stream gives wild exponents)
__global__ void k_detect(const int* __restrict__ ei, const uint16_t* __restrict__ xu,
                         int* __restrict__ flag){
  const int l = threadIdx.x;   // 64 threads
  int or_odd = ei[2*l + 1] | ei[2*(400000 + l) + 1];
  int hits = 0;
  for(int k = 0; k < 64; k++){
    int e = (xu[l*64 + k] >> 7) & 0xFF;
    hits += (e >= 200);
  }
  #pragma unroll
  for(int off=32; off; off>>=1){
    or_odd |= __shfl_xor(or_odd, off, 64);
    hits   += __shfl_xor(hits,   off, 64);
  }
  if(l == 0){
    flag[0] = (or_odd == 0) ? 1 : 0;
    flag[1] = (hits > 16) ? 1 : 0;
  }
}

__device__ __forceinline__ int load_src(const int* ei, int i, int f){
  return f ? ei[2*(size_t)i] : ei[i];
}
__device__ __forceinline__ int load_dst(const int* ei, int i, int f){
  return f ? ei[2*((size_t)N_EDGES + i)] : ei[N_EDGES + i];
}

// ---------------- canonicalize float inputs to fp32 ----------------
__global__ void k_convert(const void* x, const void* W1, const void* as1w, const void* ad1w,
                          const void* b1, const void* W2, const void* as2w, const void* ad2w,
                          const void* b2, const void* fcw, const void* fcb,
                          float* __restrict__ canon, const int* __restrict__ flag){
  int i = blockIdx.x*256 + threadIdx.x;
  if(i >= N_CANON) return;
  const void* src; int off;
  if     (i < OFF_W1 ){ src = x;    off = i; }
  else if(i < OFF_AS1){ src = W1;   off = i - OFF_W1; }
  else if(i < OFF_AD1){ src = as1w; off = i - OFF_AS1; }
  else if(i < OFF_B1 ){ src = ad1w; off = i - OFF_AD1; }
  else if(i < OFF_W2 ){ src = b1;   off = i - OFF_B1; }
  else if(i < OFF_AS2){ src = W2;   off = i - OFF_W2; }
  else if(i < OFF_AD2){ src = as2w; off = i - OFF_AS2; }
  else if(i < OFF_B2 ){ src = ad2w; off = i - OFF_AD2; }
  else if(i < OFF_FCW){ src = b2;   off = i - OFF_B2; }
  else if(i < OFF_FCB){ src = fcw;  off = i - OFF_FCW; }
  else               { src = fcb;  off = 0; }
  float v = flag[1] ? ((const float*)src)[off] : b2f(((const bf16*)src)[off]);
  canon[i] = v;
}

// ---------------- CSR build ----------------

__global__ void k_init_deg(int* deg){
  int i = blockIdx.x*256 + threadIdx.x;
  if(i < N_NODES) deg[i] = 1;            // self-loop pre-counted
}

__global__ void k_hist(const int* __restrict__ ei, int* __restrict__ deg, const int* __restrict__ flag){
  int i = blockIdx.x*256 + threadIdx.x;
  if(i < N_EDGES){
    int d = clampi(load_dst(ei, i, flag[0]), 0, N_NODES-1);
    atomicAdd(&deg[d], 1);
  }
}

__global__ __launch_bounds__(1024) void k_scan(const int* deg, int* offsets, int* cursor){
  __shared__ int wsum[16];
  __shared__ int carry_s;
  const int tid = threadIdx.x, lane = tid & 63, wid = tid >> 6;
  if(tid == 0) carry_s = 0;
  __syncthreads();
  for(int base = 0; base < N_NODES; base += 4096){
    int i0 = base + tid*4;
    int v0 = (i0+0 < N_NODES) ? deg[i0+0] : 0;
    int v1 = (i0+1 < N_NODES) ? deg[i0+1] : 0;
    int v2 = (i0+2 < N_NODES) ? deg[i0+2] : 0;
    int v3 = (i0+3 < N_NODES) ? deg[i0+3] : 0;
    int s = v0+v1+v2+v3;
    int incl = s;
    #pragma unroll
    for(int off=1; off<64; off<<=1){
      int t = __shfl_up(incl, off, 64);
      if(lane >= off) incl += t;
    }
    if(lane == 63) wsum[wid] = incl;
    __syncthreads();
    int wexcl = 0, total = 0;
    #pragma unroll
    for(int w=0; w<16; w++){
      int ws_ = wsum[w];
      if(w < wid) wexcl += ws_;
      total += ws_;
    }
    int o = carry_s + wexcl + (incl - s);
    if(i0+0 < N_NODES){ offsets[i0+0]=o; cursor[i0+0]=o; } o += v0;
    if(i0+1 < N_NODES){ offsets[i0+1]=o; cursor[i0+1]=o; } o += v1;
    if(i0+2 < N_NODES){ offsets[i0+2]=o; cursor[i0+2]=o; } o += v2;
    if(i0+3 < N_NODES){ offsets[i0+3]=o; cursor[i0+3]=o; }
    __syncthreads();
    if(tid == 0) carry_s += total;
    __syncthreads();
  }
  if(tid == 0) offsets[N_NODES] = carry_s;   // == E_TOT
}

__global__ void k_scatter(const int* __restrict__ ei, int* __restrict__ cursor, int* __restrict__ csr,
                          const int* __restrict__ flag){
  int i = blockIdx.x*256 + threadIdx.x;
  if(i >= E_TOT) return;
  int s, d;
  if(i < N_EDGES){
    int f = flag[0];
    s = clampi(load_src(ei, i, f), 0, N_NODES-1);
    d = clampi(load_dst(ei, i, f), 0, N_NODES-1);
  } else {
    s = i - N_EDGES; d = s;
  }
  int pos = atomicAdd(&cursor[d], 1);
  pos = clampi(pos, 0, E_TOT-1);
  csr[pos] = s;
}

// ---------------- Layer 1: h1 = x @ W1^T (16 -> 256), fused alpha ----------------

__global__ __launch_bounds__(256) void k_gemm1(const float* __restrict__ canon,
                        bf16* __restrict__ h1, float* __restrict__ as1, float* __restrict__ ad1){
  __shared__ __align__(16) float xs[256];    // 16 nodes x 16 features
  const int tid = threadIdx.x, lane = tid & 63, h = tid >> 6;
  const int n0 = blockIdx.x * 16;

  float w1r[16];
  #pragma unroll
  for(int k=0;k<16;k++) w1r[k] = canon[OFF_W1 + tid*16 + k];
  float asr = canon[OFF_AS1 + tid];
  float adr = canon[OFF_AD1 + tid];

  xs[tid] = canon[OFF_X + n0*16 + tid];
  __syncthreads();

  for(int nd=0; nd<16; nd++){
    const float* xr = &xs[nd*16];
    float acc = 0.f;
    #pragma unroll
    for(int k=0;k<16;k++) acc += xr[k]*w1r[k];
    int n = n0 + nd;
    h1[(size_t)n*256 + tid] = __float2bfloat16(acc);
    float vs = acc*asr, vd = acc*adr;
    #pragma unroll
    for(int off=32; off; off>>=1){ vs += __shfl_xor(vs, off, 64); vd += __shfl_xor(vd, off, 64); }
    if(lane == 0){ as1[n*4 + h] = vs; ad1[n*4 + h] = vd; }
  }
}

// ---------------- Edge weights layer 1: one wave per node, lane per CSR slot ------

__global__ __launch_bounds__(256) void k_edgew1(const int* __restrict__ offsets, const int* __restrict__ csr,
                        const float* __restrict__ as1, const float* __restrict__ ad1,
                        float* __restrict__ w1buf, float* __restrict__ den1){
  const int n = blockIdx.x*4 + (threadIdx.x >> 6);
  const int lane = threadIdx.x & 63;
  const int beg = offsets[n], end = offsets[n+1];
  const float4 ad = ((const float4*)ad1)[n];
  float d0=0.f, d1=0.f, d2=0.f, d3=0.f;
  for(int i = beg + lane; i < end; i += 64){
    int s = clampi(csr[i], 0, N_NODES-1);
    float4 as = ((const float4*)as1)[s];
    float e0 = as.x + ad.x; e0 = (e0>0.f)?e0:0.2f*e0; float w0 = __expf(fminf(e0, 60.f));
    float e1 = as.y + ad.y; e1 = (e1>0.f)?e1:0.2f*e1; float w1 = __expf(fminf(e1, 60.f));
    float e2 = as.z + ad.z; e2 = (e2>0.f)?e2:0.2f*e2; float w2 = __expf(fminf(e2, 60.f));
    float e3 = as.w + ad.w; e3 = (e3>0.f)?e3:0.2f*e3; float w3 = __expf(fminf(e3, 60.f));
    ((float4*)w1buf)[i] = make_float4(w0,w1,w2,w3);
    d0 += w0; d1 += w1; d2 += w2; d3 += w3;
  }
  #pragma unroll
  for(int off=32; off; off>>=1){
    d0 += __shfl_xor(d0, off, 64); d1 += __shfl_xor(d1, off, 64);
    d2 += __shfl_xor(d2, off, 64); d3 += __shfl_xor(d3, off, 64);
  }
  if(lane == 0) ((float4*)den1)[n] = make_float4(d0+1e-16f, d1+1e-16f, d2+1e-16f, d3+1e-16f);
}

// ---------------- Layer 1 aggregate: wave per node, lane = 4 channels -------------

__global__ __launch_bounds__(256) void k_agg1(const int* __restrict__ offsets, const int* __restrict__ csr,
                       const bf16* __restrict__ h1, const float* __restrict__ w1buf,
                       const float* __restrict__ den1, const float* __restrict__ canon,
                       bf16* __restrict__ h1o){
  const int n = blockIdx.x*4 + (threadIdx.x >> 6);
  const int lane = threadIdx.x & 63;
  const int h = lane >> 4;                         // head of channels 4*lane..4*lane+3
  const int beg = offsets[n], end = offsets[n+1];
  float a0=0.f, a1=0.f, a2=0.f, a3=0.f;
  int i = beg;
  for(; i + 1 < end; i += 2){
    int s0 = csr[i], s1 = csr[i+1];
    float w0 = w1buf[i*4 + h], w1 = w1buf[(i+1)*4 + h];
    uint2 p0 = *(const uint2*)(h1 + (size_t)s0*256 + lane*4);
    uint2 p1 = *(const uint2*)(h1 + (size_t)s1*256 + lane*4);
    a0 += w0 * bitsf(p0.x << 16); a1 += w0 * bitsf(p0.x & 0xffff0000u);
    a2 += w0 * bitsf(p0.y << 16); a3 += w0 * bitsf(p0.y & 0xffff0000u);
    a0 += w1 * bitsf(p1.x << 16); a1 += w1 * bitsf(p1.x & 0xffff0000u);
    a2 += w1 * bitsf(p1.y << 16); a3 += w1 * bitsf(p1.y & 0xffff0000u);
  }
  if(i < end){
    int s0 = csr[i];
    float w0 = w1buf[i*4 + h];
    uint2 p0 = *(const uint2*)(h1 + (size_t)s0*256 + lane*4);
    a0 += w0 * bitsf(p0.x << 16); a1 += w0 * bitsf(p0.x & 0xffff0000u);
    a2 += w0 * bitsf(p0.y << 16); a3 += w0 * bitsf(p0.y & 0xffff0000u);
  }
  float inv = 1.f / den1[n*4 + h];
  float4 bb = ((const float4*)(canon + OFF_B1))[lane];
  float o0 = a0*inv + bb.x, o1 = a1*inv + bb.y, o2 = a2*inv + bb.z, o3 = a3*inv + bb.w;
  o0 = (o0>0.f)?o0:expm1f(o0); o1 = (o1>0.f)?o1:expm1f(o1);
  o2 = (o2>0.f)?o2:expm1f(o2); o3 = (o3>0.f)?o3:expm1f(o3);
  uint2 r;
  r.x = (uint32_t)f2bfbits(o0) | ((uint32_t)f2bfbits(o1) << 16);
  r.y = (uint32_t)f2bfbits(o2) | ((uint32_t)f2bfbits(o3) << 16);
  *(uint2*)(h1o + (size_t)n*256 + lane*4) = r;
}

// ---------------- Layer 2 GEMM: h2 = h1o @ W2^T (256 -> 64), fused alpha2 ----------

__device__ __forceinline__ float2 bf16x2_to_f2(uint32_t u){
  union { uint32_t i; float f; } a, b;
  a.i = u << 16; b.i = u & 0xffff0000u;
  return make_float2(a.f, b.f);
}

__global__ __launch_bounds__(256) void k_gemm2(const bf16* __restrict__ h1o, const float* __restrict__ canon,
                        bf16* __restrict__ h2, float* __restrict__ as2, float* __restrict__ ad2){
  __shared__ uint32_t W2p[128*64];              // [kp][j] : packed bf16 (k=2kp, 2kp+1) of W2[j][k]
  __shared__ __align__(16) float hbuf[4][256];
  const int tid = threadIdx.x, j = tid & 63, nd = tid >> 6;

  for(int idx = tid; idx < 128*64; idx += 256){
    int kp = idx >> 6, jj = idx & 63;
    uint32_t lo = f2bfbits(canon[OFF_W2 + jj*256 + 2*kp    ]);
    uint32_t hi = f2bfbits(canon[OFF_W2 + jj*256 + 2*kp + 1]);
    W2p[idx] = lo | (hi << 16);
  }
  float asj = canon[OFF_AS2 + j];
  float adj = canon[OFF_AD2 + j];
  __syncthreads();

  for(int g = blockIdx.x; g < N_NODES/4; g += gridDim.x){
    int n0 = g*4;
    for(int idx = tid; idx < 1024; idx += 256){
      int nn = idx >> 8, k = idx & 255;
      hbuf[nn][k] = b2f(h1o[(size_t)(n0+nn)*256 + k]);
    }
    __syncthreads();
    const float2* hp = (const float2*)hbuf[nd];
    float acc = 0.f;
    #pragma unroll 8
    for(int kp = 0; kp < 128; kp++){
      float2 w2 = bf16x2_to_f2(W2p[kp*64 + j]);
      float2 hv = hp[kp];
      acc += hv.x*w2.x + hv.y*w2.y;
    }
    int n = n0 + nd;
    h2[(size_t)n*64 + j] = __float2bfloat16(acc);
    float vs = acc*asj, vd = acc*adj;
    #pragma unroll
    for(int off=32; off; off>>=1){ vs += __shfl_xor(vs, off, 64); vd += __shfl_xor(vd, off, 64); }
    if(j == 0){ as2[n] = vs; ad2[n] = vd; }
    __syncthreads();
  }
}

// ---------------- Edge weights layer 2 ----------------

__global__ __launch_bounds__(256) void k_edgew2(const int* __restrict__ offsets, const int* __restrict__ csr,
                        const float* __restrict__ as2, const float* __restrict__ ad2,
                        float* __restrict__ w2buf, float* __restrict__ den2){
  const int n = blockIdx.x*4 + (threadIdx.x >> 6);
  const int lane = threadIdx.x & 63;
  const int beg = offsets[n], end = offsets[n+1];
  const float ad = ad2[n];
  float d0 = 0.f;
  for(int i = beg + lane; i < end; i += 64){
    int s = clampi(csr[i], 0, N_NODES-1);
    float e = as2[s] + ad; e = (e>0.f)?e:0.2f*e;
    float w = __expf(fminf(e, 60.f));
    w2buf[i] = w;
    d0 += w;
  }
  #pragma unroll
  for(int off=32; off; off>>=1) d0 += __shfl_xor(d0, off, 64);
  if(lane == 0) den2[n] = d0 + 1e-16f;
}

// ---------------- Layer 2 aggregate + bias + ELU + FC(64->1) ----------------------

__global__ __launch_bounds__(256) void k_agg2(const int* __restrict__ offsets, const int* __restrict__ csr,
                       const bf16* __restrict__ h2, const float* __restrict__ w2buf,
                       const float* __restrict__ den2, const float* __restrict__ canon,
                       void* __restrict__ outv, const int* __restrict__ flag){
  const int n = blockIdx.x*4 + (threadIdx.x >> 6);
  const int c = threadIdx.x & 63;
  const int beg = offsets[n], end = offsets[n+1];
  float acc = 0.f;
  int i = beg;
  for(; i + 1 < end; i += 2){
    int s0 = csr[i], s1 = csr[i+1];
    float w0 = w2buf[i], w1 = w2buf[i+1];
    float v0 = b2f(h2[(size_t)s0*64 + c]);
    float v1 = b2f(h2[(size_t)s1*64 + c]);
    acc += w0*v0 + w1*v1;
  }
  if(i < end){
    int s0 = csr[i];
    acc += w2buf[i] * b2f(h2[(size_t)s0*64 + c]);
  }
  float o = acc / den2[n] + canon[OFF_B2 + c];
  o = (o > 0.f) ? o : expm1f(o);
  float v = o * canon[OFF_FCW + c];
  #pragma unroll
  for(int off=32; off; off>>=1) v += __shfl_xor(v, off, 64);
  if(c == 0){
    float r = v + canon[OFF_FCB];
    if(flag[1]) ((float*)outv)[n] = r;
    else        ((bf16*)outv)[n] = __float2bfloat16(r);
  }
}

// ---------------- launch ----------------

extern "C" void kernel_launch(void* const* d_in, const int* in_sizes, int n_in,
                              void* d_out, int out_size, void* d_ws, size_t ws_size,
                              hipStream_t stream){
  (void)in_sizes; (void)n_in; (void)out_size;
  const int* ei = (const int*)d_in[1];

  char* w = (char*)d_ws;
  auto carve = [&](size_t bytes)->char*{ char* p = w; w += (bytes + 255) & ~(size_t)255; return p; };
  int*   deg     = (int*)  carve((size_t)N_NODES*4);
  int*   offsets = (int*)  carve((size_t)(N_NODES+1)*4);
  int*   cursor  = (int*)  carve((size_t)N_NODES*4);
  int*   flag    = (int*)  carve(256);
  int*   csr     = (int*)  carve((size_t)E_TOT*4);
  float* canon   = (float*)carve((size_t)N_CANON*4);
  float* as1     = (float*)carve((size_t)N_NODES*4*4);
  float* ad1     = (float*)carve((size_t)N_NODES*4*4);
  float* as2     = (float*)carve((size_t)N_NODES*4);
  float* ad2     = (float*)carve((size_t)N_NODES*4);
  float* w1buf   = (float*)carve((size_t)E_TOT*4*4);   // w2buf aliases (dead after agg1)
  float* den1    = (float*)carve((size_t)N_NODES*4*4); // den2 aliases
  bf16*  h1      = (bf16*) carve((size_t)N_NODES*256*2);
  bf16*  h1o     = (bf16*) carve((size_t)N_NODES*256*2);
  bf16*  h2      = h1;                                  // alias: h1 dead after k_agg1
  float* w2buf   = w1buf;                               // alias: layer-1 weights dead after k_agg1
  float* den2    = den1;
  size_t required = (size_t)(w - (char*)d_ws);
  if(ws_size < required) return;               // diagnostic: output stays 0 => finite absmax

  hipLaunchKernelGGL(k_detect,   dim3(1), dim3(64), 0, stream, ei, (const uint16_t*)d_in[0], flag);
  hipLaunchKernelGGL(k_convert,  dim3((N_CANON+255)/256), dim3(256), 0, stream,
                     d_in[0], d_in[2], d_in[3], d_in[4], d_in[5], d_in[6], d_in[7], d_in[8],
                     d_in[9], d_in[10], d_in[11], canon, flag);
  hipLaunchKernelGGL(k_init_deg, dim3((N_NODES+255)/256), dim3(256), 0, stream, deg);
  hipLaunchKernelGGL(k_hist,     dim3((N_EDGES+255)/256), dim3(256), 0, stream, ei, deg, flag);
  hipLaunchKernelGGL(k_scan,     dim3(1), dim3(1024), 0, stream, deg, offsets, cursor);
  hipLaunchKernelGGL(k_scatter,  dim3((E_TOT+255)/256), dim3(256), 0, stream, ei, cursor, csr, flag);
  hipLaunchKernelGGL(k_gemm1,    dim3(N_NODES/16), dim3(256), 0, stream, canon, h1, as1, ad1);
  hipLaunchKernelGGL(k_edgew1,   dim3(N_NODES/4), dim3(256), 0, stream, offsets, csr, as1, ad1, w1buf, den1);
  hipLaunchKernelGGL(k_agg1,     dim3(N_NODES/4), dim3(256), 0, stream, offsets, csr, h1, w1buf, den1, canon, h1o);
  hipLaunchKernelGGL(k_gemm2,    dim3(1024), dim3(256), 0, stream, h1o, canon, h2, as2, ad2);
  hipLaunchKernelGGL(k_edgew2,   dim3(N_NODES/4), dim3(256), 0, stream, offsets, csr, as2, ad2, w2buf, den2);
  hipLaunchKernelGGL(k_agg2,     dim3(N_NODES/4), dim3(256), 0, stream, offsets, csr, h2, w2buf, den2, canon, d_out, flag);
}

// Round 6
// 428.963 us; speedup vs baseline: 1.6314x; 1.1427x over previous
//
#include <hip/hip_runtime.h>
#include <hip/hip_bf16.h>
#include <stdint.h>

#define N_NODES 50000
#define N_EDGES 800000
#define E_TOT   (N_EDGES + N_NODES)

// canonical fp32 buffer segment offsets (element counts)
#define OFF_X    0
#define OFF_W1   800000
#define OFF_AS1  804096
#define OFF_AD1  804352
#define OFF_B1   804608
#define OFF_W2   804864
#define OFF_AS2  821248
#define OFF_AD2  821312
#define OFF_B2   821376
#define OFF_FCW  821440
#define OFF_FCB  821504
#define N_CANON  821505

typedef __hip_bfloat16 bf16;
typedef __attribute__((ext_vector_type(8))) short short8;   // 8 bf16 = 4 VGPRs
typedef __attribute__((ext_vector_type(4))) float f32x4;

__device__ __forceinline__ float b2f(bf16 v){ return (float)v; }
__device__ __forceinline__ int clampi(int v, int lo, int hi){ return v < lo ? lo : (v > hi ? hi : v); }
__device__ __forceinline__ uint16_t f2bfbits(float f){
  union { float f; uint32_t u; } c; c.f = f;
  uint32_t r = c.u + 0x7fff + ((c.u >> 16) & 1);   // round-to-nearest-even
  return (uint16_t)(r >> 16);
}
__device__ __forceinline__ float bitsf(uint32_t u){
  union { uint32_t u; float f; } c; c.u = u; return c.f;
}

// ---------------- dtype probes (wave-parallel) ----------------
__global__ void k_detect(const int* __restrict__ ei, const uint16_t* __restrict__ xu,
                         int* __restrict__ flag){
  const int l = threadIdx.x;   // 64 threads
  int or_odd = ei[2*l + 1] | ei[2*(400000 + l) + 1];
  int hits = 0;
  for(int k = 0; k < 64; k++){
    int e = (xu[l*64 + k] >> 7) & 0xFF;
    hits += (e >= 200);
  }
  #pragma unroll
  for(int off=32; off; off>>=1){
    or_odd |= __shfl_xor(or_odd, off, 64);
    hits   += __shfl_xor(hits,   off, 64);
  }
  if(l == 0){
    flag[0] = (or_odd == 0) ? 1 : 0;
    flag[1] = (hits > 16) ? 1 : 0;
  }
}

__device__ __forceinline__ int load_src(const int* ei, int i, int f){
  return f ? ei[2*(size_t)i] : ei[i];
}
__device__ __forceinline__ int load_dst(const int* ei, int i, int f){
  return f ? ei[2*((size_t)N_EDGES + i)] : ei[N_EDGES + i];
}

// ---------------- canonicalize float inputs to fp32 ----------------
__global__ void k_convert(const void* x, const void* W1, const void* as1w, const void* ad1w,
                          const void* b1, const void* W2, const void* as2w, const void* ad2w,
                          const void* b2, const void* fcw, const void* fcb,
                          float* __restrict__ canon, const int* __restrict__ flag){
  int i = blockIdx.x*256 + threadIdx.x;
  if(i >= N_CANON) return;
  const void* src; int off;
  if     (i < OFF_W1 ){ src = x;    off = i; }
  else if(i < OFF_AS1){ src = W1;   off = i - OFF_W1; }
  else if(i < OFF_AD1){ src = as1w; off = i - OFF_AS1; }
  else if(i < OFF_B1 ){ src = ad1w; off = i - OFF_AD1; }
  else if(i < OFF_W2 ){ src = b1;   off = i - OFF_B1; }
  else if(i < OFF_AS2){ src = W2;   off = i - OFF_W2; }
  else if(i < OFF_AD2){ src = as2w; off = i - OFF_AS2; }
  else if(i < OFF_B2 ){ src = ad2w; off = i - OFF_AD2; }   // r5 regression was here (used OFF_B2)
  else if(i < OFF_FCW){ src = b2;   off = i - OFF_B2; }
  else if(i < OFF_FCB){ src = fcw;  off = i - OFF_FCW; }
  else               { src = fcb;  off = 0; }
  float v = flag[1] ? ((const float*)src)[off] : b2f(((const bf16*)src)[off]);
  canon[i] = v;
}

// W2 as bf16 [64][256] row-major (exact bits when input was bf16)
__global__ void k_w2bf(const float* __restrict__ canon, uint16_t* __restrict__ W2b){
  int i = blockIdx.x*256 + threadIdx.x;
  if(i < 16384) W2b[i] = f2bfbits(canon[OFF_W2 + i]);
}

// ---------------- CSR build ----------------

__global__ void k_init_deg(int* deg){
  int i = blockIdx.x*256 + threadIdx.x;
  if(i < N_NODES) deg[i] = 1;            // self-loop pre-counted
}

__global__ void k_hist(const int* __restrict__ ei, int* __restrict__ deg, const int* __restrict__ flag){
  int i = blockIdx.x*256 + threadIdx.x;
  if(i < N_EDGES){
    int d = clampi(load_dst(ei, i, flag[0]), 0, N_NODES-1);
    atomicAdd(&deg[d], 1);
  }
}

__global__ __launch_bounds__(1024) void k_scan(const int* deg, int* offsets, int* cursor){
  __shared__ int wsum[16];
  __shared__ int carry_s;
  const int tid = threadIdx.x, lane = tid & 63, wid = tid >> 6;
  if(tid == 0) carry_s = 0;
  __syncthreads();
  for(int base = 0; base < N_NODES; base += 4096){
    int i0 = base + tid*4;
    int v0 = (i0+0 < N_NODES) ? deg[i0+0] : 0;
    int v1 = (i0+1 < N_NODES) ? deg[i0+1] : 0;
    int v2 = (i0+2 < N_NODES) ? deg[i0+2] : 0;
    int v3 = (i0+3 < N_NODES) ? deg[i0+3] : 0;
    int s = v0+v1+v2+v3;
    int incl = s;
    #pragma unroll
    for(int off=1; off<64; off<<=1){
      int t = __shfl_up(incl, off, 64);
      if(lane >= off) incl += t;
    }
    if(lane == 63) wsum[wid] = incl;
    __syncthreads();
    int wexcl = 0, total = 0;
    #pragma unroll
    for(int w=0; w<16; w++){
      int ws_ = wsum[w];
      if(w < wid) wexcl += ws_;
      total += ws_;
    }
    int o = carry_s + wexcl + (incl - s);
    if(i0+0 < N_NODES){ offsets[i0+0]=o; cursor[i0+0]=o; } o += v0;
    if(i0+1 < N_NODES){ offsets[i0+1]=o; cursor[i0+1]=o; } o += v1;
    if(i0+2 < N_NODES){ offsets[i0+2]=o; cursor[i0+2]=o; } o += v2;
    if(i0+3 < N_NODES){ offsets[i0+3]=o; cursor[i0+3]=o; }
    __syncthreads();
    if(tid == 0) carry_s += total;
    __syncthreads();
  }
  if(tid == 0) offsets[N_NODES] = carry_s;   // == E_TOT
}

__global__ void k_scatter(const int* __restrict__ ei, int* __restrict__ cursor, int* __restrict__ csr,
                          const int* __restrict__ flag){
  int i = blockIdx.x*256 + threadIdx.x;
  if(i >= E_TOT) return;
  int s, d;
  if(i < N_EDGES){
    int f = flag[0];
    s = clampi(load_src(ei, i, f), 0, N_NODES-1);
    d = clampi(load_dst(ei, i, f), 0, N_NODES-1);
  } else {
    s = i - N_EDGES; d = s;
  }
  int pos = atomicAdd(&cursor[d], 1);
  pos = clampi(pos, 0, E_TOT-1);
  csr[pos] = s;
}

// ---------------- Layer 1: h1 = x @ W1^T (16 -> 256), fused alpha ----------------

__global__ __launch_bounds__(256) void k_gemm1(const float* __restrict__ canon,
                        bf16* __restrict__ h1, float* __restrict__ as1, float* __restrict__ ad1){
  __shared__ __align__(16) float xs[256];    // 16 nodes x 16 features
  const int tid = threadIdx.x, lane = tid & 63, h = tid >> 6;
  const int n0 = blockIdx.x * 16;

  float w1r[16];
  #pragma unroll
  for(int k=0;k<16;k++) w1r[k] = canon[OFF_W1 + tid*16 + k];
  float asr = canon[OFF_AS1 + tid];
  float adr = canon[OFF_AD1 + tid];

  xs[tid] = canon[OFF_X + n0*16 + tid];
  __syncthreads();

  for(int nd=0; nd<16; nd++){
    const float* xr = &xs[nd*16];
    float acc = 0.f;
    #pragma unroll
    for(int k=0;k<16;k++) acc += xr[k]*w1r[k];
    int n = n0 + nd;
    h1[(size_t)n*256 + tid] = __float2bfloat16(acc);
    float vs = acc*asr, vd = acc*adr;
    #pragma unroll
    for(int off=32; off; off>>=1){ vs += __shfl_xor(vs, off, 64); vd += __shfl_xor(vd, off, 64); }
    if(lane == 0){ as1[n*4 + h] = vs; ad1[n*4 + h] = vd; }
  }
}

// ---------------- Edge weights layer 1 ----------------

__global__ __launch_bounds__(256) void k_edgew1(const int* __restrict__ offsets, const int* __restrict__ csr,
                        const float* __restrict__ as1, const float* __restrict__ ad1,
                        float* __restrict__ w1buf, float* __restrict__ den1){
  const int n = blockIdx.x*4 + (threadIdx.x >> 6);
  const int lane = threadIdx.x & 63;
  const int beg = offsets[n], end = offsets[n+1];
  const float4 ad = ((const float4*)ad1)[n];
  float d0=0.f, d1=0.f, d2=0.f, d3=0.f;
  for(int i = beg + lane; i < end; i += 64){
    int s = clampi(csr[i], 0, N_NODES-1);
    float4 as = ((const float4*)as1)[s];
    float e0 = as.x + ad.x; e0 = (e0>0.f)?e0:0.2f*e0; float w0 = __expf(fminf(e0, 60.f));
    float e1 = as.y + ad.y; e1 = (e1>0.f)?e1:0.2f*e1; float w1 = __expf(fminf(e1, 60.f));
    float e2 = as.z + ad.z; e2 = (e2>0.f)?e2:0.2f*e2; float w2 = __expf(fminf(e2, 60.f));
    float e3 = as.w + ad.w; e3 = (e3>0.f)?e3:0.2f*e3; float w3 = __expf(fminf(e3, 60.f));
    ((float4*)w1buf)[i] = make_float4(w0,w1,w2,w3);
    d0 += w0; d1 += w1; d2 += w2; d3 += w3;
  }
  #pragma unroll
  for(int off=32; off; off>>=1){
    d0 += __shfl_xor(d0, off, 64); d1 += __shfl_xor(d1, off, 64);
    d2 += __shfl_xor(d2, off, 64); d3 += __shfl_xor(d3, off, 64);
  }
  if(lane == 0) ((float4*)den1)[n] = make_float4(d0+1e-16f, d1+1e-16f, d2+1e-16f, d3+1e-16f);
}

// ---------------- Layer 1 aggregate: wave per node, lane = 4 channels -------------

__global__ __launch_bounds__(256) void k_agg1(const int* __restrict__ offsets, const int* __restrict__ csr,
                       const bf16* __restrict__ h1, const float* __restrict__ w1buf,
                       const float* __restrict__ den1, const float* __restrict__ canon,
                       bf16* __restrict__ h1o){
  const int n = blockIdx.x*4 + (threadIdx.x >> 6);
  const int lane = threadIdx.x & 63;
  const int h = lane >> 4;
  const int beg = offsets[n], end = offsets[n+1];
  float a0=0.f, a1=0.f, a2=0.f, a3=0.f;
  int i = beg;
  for(; i + 1 < end; i += 2){
    int s0 = csr[i], s1 = csr[i+1];
    float w0 = w1buf[i*4 + h], w1 = w1buf[(i+1)*4 + h];
    uint2 p0 = *(const uint2*)(h1 + (size_t)s0*256 + lane*4);
    uint2 p1 = *(const uint2*)(h1 + (size_t)s1*256 + lane*4);
    a0 += w0 * bitsf(p0.x << 16); a1 += w0 * bitsf(p0.x & 0xffff0000u);
    a2 += w0 * bitsf(p0.y << 16); a3 += w0 * bitsf(p0.y & 0xffff0000u);
    a0 += w1 * bitsf(p1.x << 16); a1 += w1 * bitsf(p1.x & 0xffff0000u);
    a2 += w1 * bitsf(p1.y << 16); a3 += w1 * bitsf(p1.y & 0xffff0000u);
  }
  if(i < end){
    int s0 = csr[i];
    float w0 = w1buf[i*4 + h];
    uint2 p0 = *(const uint2*)(h1 + (size_t)s0*256 + lane*4);
    a0 += w0 * bitsf(p0.x << 16); a1 += w0 * bitsf(p0.x & 0xffff0000u);
    a2 += w0 * bitsf(p0.y << 16); a3 += w0 * bitsf(p0.y & 0xffff0000u);
  }
  float inv = 1.f / den1[n*4 + h];
  float4 bb = ((const float4*)(canon + OFF_B1))[lane];
  float o0 = a0*inv + bb.x, o1 = a1*inv + bb.y, o2 = a2*inv + bb.z, o3 = a3*inv + bb.w;
  o0 = (o0>0.f)?o0:expm1f(o0); o1 = (o1>0.f)?o1:expm1f(o1);
  o2 = (o2>0.f)?o2:expm1f(o2); o3 = (o3>0.f)?o3:expm1f(o3);
  uint2 r;
  r.x = (uint32_t)f2bfbits(o0) | ((uint32_t)f2bfbits(o1) << 16);
  r.y = (uint32_t)f2bfbits(o2) | ((uint32_t)f2bfbits(o3) << 16);
  *(uint2*)(h1o + (size_t)n*256 + lane*4) = r;
}

// ---------------- Layer 2 GEMM via MFMA: [50000x256]x[256x64], fused alpha2 -------
// Wave-per-16-node tile. A = h1o rows (bf16 row-major, fragment-contiguous),
// B = W2b [n][k] row-major == B^T (fragment-contiguous). B held in registers.

__global__ __launch_bounds__(256) void k_gemm2(const bf16* __restrict__ h1o, const uint16_t* __restrict__ W2b,
                        const float* __restrict__ canon,
                        bf16* __restrict__ h2, float* __restrict__ as2, float* __restrict__ ad2){
  const int tid = threadIdx.x, lane = tid & 63, wave = tid >> 6;
  const int quad = lane >> 4, c = lane & 15;

  // B fragments: bfrag[cb][ks] = W2b[cb*16+c][ks*32 + quad*8 .. +7]
  short8 bfrag[4][8];
  #pragma unroll
  for(int cb=0; cb<4; cb++)
    #pragma unroll
    for(int ks=0; ks<8; ks++)
      bfrag[cb][ks] = *(const short8*)(W2b + (cb*16 + c)*256 + ks*32 + quad*8);

  float asj[4], adj[4];
  #pragma unroll
  for(int cb=0; cb<4; cb++){
    asj[cb] = canon[OFF_AS2 + cb*16 + c];
    adj[cb] = canon[OFF_AD2 + cb*16 + c];
  }

  const int tiles = N_NODES/16;                 // 3125
  const int gw = blockIdx.x*4 + wave, nw = gridDim.x*4;
  for(int t = gw; t < tiles; t += nw){
    const int n0 = t*16;
    f32x4 acc[4];
    #pragma unroll
    for(int cb=0; cb<4; cb++) acc[cb] = (f32x4){0.f,0.f,0.f,0.f};

    const bf16* arow = h1o + (size_t)(n0 + c)*256 + quad*8;
    #pragma unroll
    for(int ks=0; ks<8; ks++){
      short8 af = *(const short8*)(arow + ks*32);
      acc[0] = __builtin_amdgcn_mfma_f32_16x16x32_bf16(af, bfrag[0][ks], acc[0], 0,0,0);
      acc[1] = __builtin_amdgcn_mfma_f32_16x16x32_bf16(af, bfrag[1][ks], acc[1], 0,0,0);
      acc[2] = __builtin_amdgcn_mfma_f32_16x16x32_bf16(af, bfrag[2][ks], acc[2], 0,0,0);
      acc[3] = __builtin_amdgcn_mfma_f32_16x16x32_bf16(af, bfrag[3][ks], acc[3], 0,0,0);
    }

    // C/D layout: col = c (+16*cb), row = quad*4 + r
    float vs[4] = {0.f,0.f,0.f,0.f}, vd[4] = {0.f,0.f,0.f,0.f};
    #pragma unroll
    for(int cb=0; cb<4; cb++)
      #pragma unroll
      for(int r=0; r<4; r++){
        float v = acc[cb][r];
        h2[(size_t)(n0 + quad*4 + r)*64 + cb*16 + c] = __float2bfloat16(v);
        vs[r] += v * asj[cb];
        vd[r] += v * adj[cb];
      }
    #pragma unroll
    for(int r=0; r<4; r++){
      #pragma unroll
      for(int off=1; off<16; off<<=1){
        vs[r] += __shfl_xor(vs[r], off, 64);
        vd[r] += __shfl_xor(vd[r], off, 64);
      }
    }
    if(c == 0){
      #pragma unroll
      for(int r=0; r<4; r++){
        as2[n0 + quad*4 + r] = vs[r];
        ad2[n0 + quad*4 + r] = vd[r];
      }
    }
  }
}

// ---------------- Edge weights layer 2 ----------------

__global__ __launch_bounds__(256) void k_edgew2(const int* __restrict__ offsets, const int* __restrict__ csr,
                        const float* __restrict__ as2, const float* __restrict__ ad2,
                        float* __restrict__ w2buf, float* __restrict__ den2){
  const int n = blockIdx.x*4 + (threadIdx.x >> 6);
  const int lane = threadIdx.x & 63;
  const int beg = offsets[n], end = offsets[n+1];
  const float ad = ad2[n];
  float d0 = 0.f;
  for(int i = beg + lane; i < end; i += 64){
    int s = clampi(csr[i], 0, N_NODES-1);
    float e = as2[s] + ad; e = (e>0.f)?e:0.2f*e;
    float w = __expf(fminf(e, 60.f));
    w2buf[i] = w;
    d0 += w;
  }
  #pragma unroll
  for(int off=32; off; off>>=1) d0 += __shfl_xor(d0, off, 64);
  if(lane == 0) den2[n] = d0 + 1e-16f;
}

// ---------------- Layer 2 aggregate + bias + ELU + FC(64->1) ----------------------

__global__ __launch_bounds__(256) void k_agg2(const int* __restrict__ offsets, const int* __restrict__ csr,
                       const bf16* __restrict__ h2, const float* __restrict__ w2buf,
                       const float* __restrict__ den2, const float* __restrict__ canon,
                       void* __restrict__ outv, const int* __restrict__ flag){
  const int n = blockIdx.x*4 + (threadIdx.x >> 6);
  const int c = threadIdx.x & 63;
  const int beg = offsets[n], end = offsets[n+1];
  float acc = 0.f;
  int i = beg;
  for(; i + 1 < end; i += 2){
    int s0 = csr[i], s1 = csr[i+1];
    float w0 = w2buf[i], w1 = w2buf[i+1];
    float v0 = b2f(h2[(size_t)s0*64 + c]);
    float v1 = b2f(h2[(size_t)s1*64 + c]);
    acc += w0*v0 + w1*v1;
  }
  if(i < end){
    int s0 = csr[i];
    acc += w2buf[i] * b2f(h2[(size_t)s0*64 + c]);
  }
  float o = acc / den2[n] + canon[OFF_B2 + c];
  o = (o > 0.f) ? o : expm1f(o);
  float v = o * canon[OFF_FCW + c];
  #pragma unroll
  for(int off=32; off; off>>=1) v += __shfl_xor(v, off, 64);
  if(c == 0){
    float r = v + canon[OFF_FCB];
    if(flag[1]) ((float*)outv)[n] = r;
    else        ((bf16*)outv)[n] = __float2bfloat16(r);
  }
}

// ---------------- launch ----------------

extern "C" void kernel_launch(void* const* d_in, const int* in_sizes, int n_in,
                              void* d_out, int out_size, void* d_ws, size_t ws_size,
                              hipStream_t stream){
  (void)in_sizes; (void)n_in; (void)out_size;
  const int* ei = (const int*)d_in[1];

  char* w = (char*)d_ws;
  auto carve = [&](size_t bytes)->char*{ char* p = w; w += (bytes + 255) & ~(size_t)255; return p; };
  int*      deg     = (int*)     carve((size_t)N_NODES*4);
  int*      offsets = (int*)     carve((size_t)(N_NODES+1)*4);
  int*      cursor  = (int*)     carve((size_t)N_NODES*4);
  int*      flag    = (int*)     carve(256);
  int*      csr     = (int*)     carve((size_t)E_TOT*4);
  float*    canon   = (float*)   carve((size_t)N_CANON*4);
  uint16_t* W2b     = (uint16_t*)carve((size_t)16384*2);
  float*    as1     = (float*)   carve((size_t)N_NODES*4*4);
  float*    ad1     = (float*)   carve((size_t)N_NODES*4*4);
  float*    as2     = (float*)   carve((size_t)N_NODES*4);
  float*    ad2     = (float*)   carve((size_t)N_NODES*4);
  float*    w1buf   = (float*)   carve((size_t)E_TOT*4*4);   // w2buf aliases (dead after agg1)
  float*    den1    = (float*)   carve((size_t)N_NODES*4*4); // den2 aliases
  bf16*     h1      = (bf16*)    carve((size_t)N_NODES*256*2);
  bf16*     h1o     = (bf16*)    carve((size_t)N_NODES*256*2);
  bf16*     h2      = h1;                                    // alias: h1 dead after k_agg1
  float*    w2buf   = w1buf;
  float*    den2    = den1;
  size_t required = (size_t)(w - (char*)d_ws);
  if(ws_size < required) return;               // diagnostic: output stays 0 => finite absmax

  hipLaunchKernelGGL(k_detect,   dim3(1), dim3(64), 0, stream, ei, (const uint16_t*)d_in[0], flag);
  hipLaunchKernelGGL(k_convert,  dim3((N_CANON+255)/256), dim3(256), 0, stream,
                     d_in[0], d_in[2], d_in[3], d_in[4], d_in[5], d_in[6], d_in[7], d_in[8],
                     d_in[9], d_in[10], d_in[11], canon, flag);
  hipLaunchKernelGGL(k_w2bf,     dim3(64), dim3(256), 0, stream, canon, W2b);
  hipLaunchKernelGGL(k_init_deg, dim3((N_NODES+255)/256), dim3(256), 0, stream, deg);
  hipLaunchKernelGGL(k_hist,     dim3((N_EDGES+255)/256), dim3(256), 0, stream, ei, deg, flag);
  hipLaunchKernelGGL(k_scan,     dim3(1), dim3(1024), 0, stream, deg, offsets, cursor);
  hipLaunchKernelGGL(k_scatter,  dim3((E_TOT+255)/256), dim3(256), 0, stream, ei, cursor, csr, flag);
  hipLaunchKernelGGL(k_gemm1,    dim3(N_NODES/16), dim3(256), 0, stream, canon, h1, as1, ad1);
  hipLaunchKernelGGL(k_edgew1,   dim3(N_NODES/4), dim3(256), 0, stream, offsets, csr, as1, ad1, w1buf, den1);
  hipLaunchKernelGGL(k_agg1,     dim3(N_NODES/4), dim3(256), 0, stream, offsets, csr, h1, w1buf, den1, canon, h1o);
  hipLaunchKernelGGL(k_gemm2,    dim3(782), dim3(256), 0, stream, h1o, W2b, canon, h2, as2, ad2);
  hipLaunchKernelGGL(k_edgew2,   dim3(N_NODES/4), dim3(256), 0, stream, offsets, csr, as2, ad2, w2buf, den2);
  hipLaunchKernelGGL(k_agg2,     dim3(N_NODES/4), dim3(256), 0, stream, offsets, csr, h2, w2buf, den2, canon, d_out, flag);
}

// Round 7
// 413.991 us; speedup vs baseline: 1.6904x; 1.0362x over previous
//
#include <hip/hip_runtime.h>
#include <hip/hip_bf16.h>
#include <stdint.h>

#define N_NODES 50000
#define N_EDGES 800000
#define E_TOT   (N_EDGES + N_NODES)

// canonical fp32 buffer segment offsets (element counts)
#define OFF_X    0
#define OFF_W1   800000
#define OFF_AS1  804096
#define OFF_AD1  804352
#define OFF_B1   804608
#define OFF_W2   804864
#define OFF_AS2  821248
#define OFF_AD2  821312
#define OFF_B2   821376
#define OFF_FCW  821440
#define OFF_FCB  821504
#define N_CANON  821505

typedef __hip_bfloat16 bf16;
typedef __attribute__((ext_vector_type(8))) short short8;   // 8 bf16 = 4 VGPRs
typedef __attribute__((ext_vector_type(4))) float f32x4;

__device__ __forceinline__ float b2f(bf16 v){ return (float)v; }
__device__ __forceinline__ int clampi(int v, int lo, int hi){ return v < lo ? lo : (v > hi ? hi : v); }
__device__ __forceinline__ uint16_t f2bfbits(float f){
  union { float f; uint32_t u; } c; c.f = f;
  uint32_t r = c.u + 0x7fff + ((c.u >> 16) & 1);   // round-to-nearest-even
  return (uint16_t)(r >> 16);
}
__device__ __forceinline__ float bitsf(uint32_t u){
  union { uint32_t u; float f; } c; c.u = u; return c.f;
}

__device__ __forceinline__ int load_src(const int* ei, int i, int f){
  return f ? ei[2*(size_t)i] : ei[i];
}
__device__ __forceinline__ int load_dst(const int* ei, int i, int f){
  return f ? ei[2*((size_t)N_EDGES + i)] : ei[N_EDGES + i];
}

// ---------------- init: deg=1 everywhere + dtype probes (merged launch) ----------
__global__ void k_init(int* __restrict__ deg, const int* __restrict__ ei,
                       const uint16_t* __restrict__ xu, int* __restrict__ flag){
  if(blockIdx.x < 196){
    int i = blockIdx.x*256 + threadIdx.x;
    if(i < N_NODES) deg[i] = 1;            // self-loop pre-counted
    return;
  }
  const int l = threadIdx.x;
  if(l >= 64) return;
  int or_odd = ei[2*l + 1] | ei[2*(400000 + l) + 1];
  int hits = 0;
  for(int k = 0; k < 64; k++){
    int e = (xu[l*64 + k] >> 7) & 0xFF;
    hits += (e >= 200);
  }
  #pragma unroll
  for(int off=32; off; off>>=1){
    or_odd |= __shfl_xor(or_odd, off, 64);
    hits   += __shfl_xor(hits,   off, 64);
  }
  if(l == 0){
    flag[0] = (or_odd == 0) ? 1 : 0;   // int64 edge_index
    flag[1] = (hits > 16) ? 1 : 0;     // fp32 float inputs
  }
}

// ---------------- canonicalize float inputs to fp32 ----------------
__global__ void k_convert(const void* x, const void* W1, const void* as1w, const void* ad1w,
                          const void* b1, const void* W2, const void* as2w, const void* ad2w,
                          const void* b2, const void* fcw, const void* fcb,
                          float* __restrict__ canon, const int* __restrict__ flag){
  int i = blockIdx.x*256 + threadIdx.x;
  if(i >= N_CANON) return;
  const void* src; int off;
  if     (i < OFF_W1 ){ src = x;    off = i; }
  else if(i < OFF_AS1){ src = W1;   off = i - OFF_W1; }
  else if(i < OFF_AD1){ src = as1w; off = i - OFF_AS1; }
  else if(i < OFF_B1 ){ src = ad1w; off = i - OFF_AD1; }
  else if(i < OFF_W2 ){ src = b1;   off = i - OFF_B1; }
  else if(i < OFF_AS2){ src = W2;   off = i - OFF_W2; }
  else if(i < OFF_AD2){ src = as2w; off = i - OFF_AS2; }
  else if(i < OFF_B2 ){ src = ad2w; off = i - OFF_AD2; }
  else if(i < OFF_FCW){ src = b2;   off = i - OFF_B2; }
  else if(i < OFF_FCB){ src = fcw;  off = i - OFF_FCW; }
  else               { src = fcb;  off = 0; }
  float v = flag[1] ? ((const float*)src)[off] : b2f(((const bf16*)src)[off]);
  canon[i] = v;
}

// W2 as bf16 [64][256] row-major (exact bits when input was bf16)
__global__ void k_w2bf(const float* __restrict__ canon, uint16_t* __restrict__ W2b){
  int i = blockIdx.x*256 + threadIdx.x;
  if(i < 16384) W2b[i] = f2bfbits(canon[OFF_W2 + i]);
}

// ---------------- CSR build ----------------

__global__ void k_hist(const int* __restrict__ ei, int* __restrict__ deg, const int* __restrict__ flag){
  int i = blockIdx.x*256 + threadIdx.x;
  if(i < N_EDGES){
    int d = clampi(load_dst(ei, i, flag[0]), 0, N_NODES-1);
    atomicAdd(&deg[d], 1);
  }
}

__global__ __launch_bounds__(1024) void k_scan(const int* deg, int* offsets, int* cursor){
  __shared__ int wsum[16];
  __shared__ int carry_s;
  const int tid = threadIdx.x, lane = tid & 63, wid = tid >> 6;
  if(tid == 0) carry_s = 0;
  __syncthreads();
  for(int base = 0; base < N_NODES; base += 4096){
    int i0 = base + tid*4;
    int v0 = (i0+0 < N_NODES) ? deg[i0+0] : 0;
    int v1 = (i0+1 < N_NODES) ? deg[i0+1] : 0;
    int v2 = (i0+2 < N_NODES) ? deg[i0+2] : 0;
    int v3 = (i0+3 < N_NODES) ? deg[i0+3] : 0;
    int s = v0+v1+v2+v3;
    int incl = s;
    #pragma unroll
    for(int off=1; off<64; off<<=1){
      int t = __shfl_up(incl, off, 64);
      if(lane >= off) incl += t;
    }
    if(lane == 63) wsum[wid] = incl;
    __syncthreads();
    int wexcl = 0, total = 0;
    #pragma unroll
    for(int w=0; w<16; w++){
      int ws_ = wsum[w];
      if(w < wid) wexcl += ws_;
      total += ws_;
    }
    int o = carry_s + wexcl + (incl - s);
    if(i0+0 < N_NODES){ offsets[i0+0]=o; cursor[i0+0]=o; } o += v0;
    if(i0+1 < N_NODES){ offsets[i0+1]=o; cursor[i0+1]=o; } o += v1;
    if(i0+2 < N_NODES){ offsets[i0+2]=o; cursor[i0+2]=o; } o += v2;
    if(i0+3 < N_NODES){ offsets[i0+3]=o; cursor[i0+3]=o; }
    __syncthreads();
    if(tid == 0) carry_s += total;
    __syncthreads();
  }
  if(tid == 0) offsets[N_NODES] = carry_s;   // == E_TOT
}

__global__ void k_scatter(const int* __restrict__ ei, int* __restrict__ cursor, int* __restrict__ csr,
                          const int* __restrict__ flag){
  int i = blockIdx.x*256 + threadIdx.x;
  if(i >= E_TOT) return;
  int s, d;
  if(i < N_EDGES){
    int f = flag[0];
    s = clampi(load_src(ei, i, f), 0, N_NODES-1);
    d = clampi(load_dst(ei, i, f), 0, N_NODES-1);
  } else {
    s = i - N_EDGES; d = s;
  }
  int pos = atomicAdd(&cursor[d], 1);
  pos = clampi(pos, 0, E_TOT-1);
  csr[pos] = s;
}

// ---------------- Layer 1 alpha: as1/ad1 = X @ p^T via folded attention ----------
// p_src[h,k] = sum_c a_src[h,c]*W1[h*64+c,k]  (exact linear fold; no h1 needed)

__global__ __launch_bounds__(256) void k_alpha1(const float* __restrict__ canon,
                        float* __restrict__ as1, float* __restrict__ ad1){
  __shared__ float ps[64], pd[64];
  const int tid = threadIdx.x;
  if(tid < 128){
    int e = tid & 63;                    // h*16+k
    int h = e >> 4, k = e & 15;
    const float* av = canon + (tid < 64 ? OFF_AS1 : OFF_AD1) + h*64;
    const float* Wp = canon + OFF_W1 + (h*64)*16 + k;
    float acc = 0.f;
    #pragma unroll 8
    for(int c = 0; c < 64; c++) acc += av[c] * Wp[c*16];
    (tid < 64 ? ps : pd)[e] = acc;
  }
  __syncthreads();
  int n = blockIdx.x*256 + tid;
  if(n >= N_NODES) return;
  float xr[16];
  const float4* xp = (const float4*)(canon + OFF_X + n*16);
  #pragma unroll
  for(int t=0;t<4;t++){ float4 v = xp[t]; xr[4*t]=v.x; xr[4*t+1]=v.y; xr[4*t+2]=v.z; xr[4*t+3]=v.w; }
  float s[4], d[4];
  #pragma unroll
  for(int h=0;h<4;h++){
    float a=0.f, b=0.f;
    #pragma unroll
    for(int k=0;k<16;k++){ a += ps[h*16+k]*xr[k]; b += pd[h*16+k]*xr[k]; }
    s[h]=a; d[h]=b;
  }
  ((float4*)as1)[n] = make_float4(s[0],s[1],s[2],s[3]);
  ((float4*)ad1)[n] = make_float4(d[0],d[1],d[2],d[3]);
}

// ---------------- Edge weights layer 1 ----------------

__global__ __launch_bounds__(256) void k_edgew1(const int* __restrict__ offsets, const int* __restrict__ csr,
                        const float* __restrict__ as1, const float* __restrict__ ad1,
                        float* __restrict__ w1buf, float* __restrict__ den1){
  const int n = blockIdx.x*4 + (threadIdx.x >> 6);
  const int lane = threadIdx.x & 63;
  const int beg = offsets[n], end = offsets[n+1];
  const float4 ad = ((const float4*)ad1)[n];
  float d0=0.f, d1=0.f, d2=0.f, d3=0.f;
  for(int i = beg + lane; i < end; i += 64){
    int s = clampi(csr[i], 0, N_NODES-1);
    float4 as = ((const float4*)as1)[s];
    float e0 = as.x + ad.x; e0 = (e0>0.f)?e0:0.2f*e0; float w0 = __expf(fminf(e0, 60.f));
    float e1 = as.y + ad.y; e1 = (e1>0.f)?e1:0.2f*e1; float w1 = __expf(fminf(e1, 60.f));
    float e2 = as.z + ad.z; e2 = (e2>0.f)?e2:0.2f*e2; float w2 = __expf(fminf(e2, 60.f));
    float e3 = as.w + ad.w; e3 = (e3>0.f)?e3:0.2f*e3; float w3 = __expf(fminf(e3, 60.f));
    ((float4*)w1buf)[i] = make_float4(w0,w1,w2,w3);
    d0 += w0; d1 += w1; d2 += w2; d3 += w3;
  }
  #pragma unroll
  for(int off=32; off; off>>=1){
    d0 += __shfl_xor(d0, off, 64); d1 += __shfl_xor(d1, off, 64);
    d2 += __shfl_xor(d2, off, 64); d3 += __shfl_xor(d3, off, 64);
  }
  if(lane == 0) ((float4*)den1)[n] = make_float4(d0+1e-16f, d1+1e-16f, d2+1e-16f, d3+1e-16f);
}

// ---------------- Layer 1 aggregate on RAW x (64B rows, L2-resident), fused W1+ELU
// wave per node; lane = (h = lane>>4, k = lane&15); y[h][k] = sum_s w*x[s][k].
// out[n][h*64+c] = ELU( W1[h*64+c,:]·(y[h]/den) + b1 ).  Lane's 4 channels = lane*4..+3.

__global__ __launch_bounds__(256) void k_agg1(const int* __restrict__ offsets, const int* __restrict__ csr,
                       const float* __restrict__ canon, const float* __restrict__ w1buf,
                       const float* __restrict__ den1, bf16* __restrict__ h1o){
  __shared__ __align__(16) float yls[4][64];
  const int wv = threadIdx.x >> 6, lane = threadIdx.x & 63;
  const int h = lane >> 4, k = lane & 15;

  float w1f[64];                                   // W1 rows lane*4..lane*4+3
  const float4* wsrc = (const float4*)(canon + OFF_W1 + lane*64);
  #pragma unroll
  for(int t=0;t<16;t++){
    float4 v = wsrc[t];
    w1f[4*t]=v.x; w1f[4*t+1]=v.y; w1f[4*t+2]=v.z; w1f[4*t+3]=v.w;
  }
  float4 bb = ((const float4*)(canon + OFF_B1))[lane];
  const float* xf = canon + OFF_X;

  for(int n = blockIdx.x*4 + wv; n < N_NODES; n += gridDim.x*4){
    const int beg = offsets[n], end = offsets[n+1];
    float y = 0.f;
    int i = beg;
    for(; i + 1 < end; i += 2){
      int s0 = csr[i], s1 = csr[i+1];
      float w0 = w1buf[i*4 + h], w1v = w1buf[(i+1)*4 + h];
      float x0 = xf[s0*16 + k], x1 = xf[s1*16 + k];
      y += w0*x0 + w1v*x1;
    }
    if(i < end){
      int s0 = csr[i];
      y += w1buf[i*4 + h] * xf[s0*16 + k];
    }
    float inv = 1.f / den1[n*4 + h];
    yls[wv][lane] = y * inv;
    __builtin_amdgcn_s_waitcnt(0);                 // drain lds write (same wave)
    const float4* yh = (const float4*)&yls[wv][h*16];
    float4 y0 = yh[0], y1 = yh[1], y2 = yh[2], y3 = yh[3];
    float o[4];
    #pragma unroll
    for(int c=0;c<4;c++){
      const float* wf = &w1f[c*16];
      float a;
      a  = wf[0]*y0.x + wf[1]*y0.y + wf[2]*y0.z  + wf[3]*y0.w;
      a += wf[4]*y1.x + wf[5]*y1.y + wf[6]*y1.z  + wf[7]*y1.w;
      a += wf[8]*y2.x + wf[9]*y2.y + wf[10]*y2.z + wf[11]*y2.w;
      a += wf[12]*y3.x+ wf[13]*y3.y+ wf[14]*y3.z + wf[15]*y3.w;
      o[c] = a;
    }
    o[0]+=bb.x; o[1]+=bb.y; o[2]+=bb.z; o[3]+=bb.w;
    #pragma unroll
    for(int c=0;c<4;c++) o[c] = (o[c] > 0.f) ? o[c] : expm1f(o[c]);
    uint2 r;
    r.x = (uint32_t)f2bfbits(o[0]) | ((uint32_t)f2bfbits(o[1]) << 16);
    r.y = (uint32_t)f2bfbits(o[2]) | ((uint32_t)f2bfbits(o[3]) << 16);
    *(uint2*)(h1o + (size_t)n*256 + lane*4) = r;
  }
}

// ---------------- Layer 2 GEMM via MFMA: [50000x256]x[256x64], fused alpha2 -------

__global__ __launch_bounds__(256) void k_gemm2(const bf16* __restrict__ h1o, const uint16_t* __restrict__ W2b,
                        const float* __restrict__ canon,
                        bf16* __restrict__ h2, float* __restrict__ as2, float* __restrict__ ad2){
  const int tid = threadIdx.x, lane = tid & 63, wave = tid >> 6;
  const int quad = lane >> 4, c = lane & 15;

  short8 bfrag[4][8];
  #pragma unroll
  for(int cb=0; cb<4; cb++)
    #pragma unroll
    for(int ks=0; ks<8; ks++)
      bfrag[cb][ks] = *(const short8*)(W2b + (cb*16 + c)*256 + ks*32 + quad*8);

  float asj[4], adj[4];
  #pragma unroll
  for(int cb=0; cb<4; cb++){
    asj[cb] = canon[OFF_AS2 + cb*16 + c];
    adj[cb] = canon[OFF_AD2 + cb*16 + c];
  }

  const int tiles = N_NODES/16;                 // 3125
  const int gw = blockIdx.x*4 + wave, nw = gridDim.x*4;
  for(int t = gw; t < tiles; t += nw){
    const int n0 = t*16;
    f32x4 acc[4];
    #pragma unroll
    for(int cb=0; cb<4; cb++) acc[cb] = (f32x4){0.f,0.f,0.f,0.f};

    const bf16* arow = h1o + (size_t)(n0 + c)*256 + quad*8;
    #pragma unroll
    for(int ks=0; ks<8; ks++){
      short8 af = *(const short8*)(arow + ks*32);
      acc[0] = __builtin_amdgcn_mfma_f32_16x16x32_bf16(af, bfrag[0][ks], acc[0], 0,0,0);
      acc[1] = __builtin_amdgcn_mfma_f32_16x16x32_bf16(af, bfrag[1][ks], acc[1], 0,0,0);
      acc[2] = __builtin_amdgcn_mfma_f32_16x16x32_bf16(af, bfrag[2][ks], acc[2], 0,0,0);
      acc[3] = __builtin_amdgcn_mfma_f32_16x16x32_bf16(af, bfrag[3][ks], acc[3], 0,0,0);
    }

    float vs[4] = {0.f,0.f,0.f,0.f}, vd[4] = {0.f,0.f,0.f,0.f};
    #pragma unroll
    for(int cb=0; cb<4; cb++)
      #pragma unroll
      for(int r=0; r<4; r++){
        float v = acc[cb][r];
        h2[(size_t)(n0 + quad*4 + r)*64 + cb*16 + c] = __float2bfloat16(v);
        vs[r] += v * asj[cb];
        vd[r] += v * adj[cb];
      }
    #pragma unroll
    for(int r=0; r<4; r++){
      #pragma unroll
      for(int off=1; off<16; off<<=1){
        vs[r] += __shfl_xor(vs[r], off, 64);
        vd[r] += __shfl_xor(vd[r], off, 64);
      }
    }
    if(c == 0){
      #pragma unroll
      for(int r=0; r<4; r++){
        as2[n0 + quad*4 + r] = vs[r];
        ad2[n0 + quad*4 + r] = vd[r];
      }
    }
  }
}

// ---------------- Edge weights layer 2 ----------------

__global__ __launch_bounds__(256) void k_edgew2(const int* __restrict__ offsets, const int* __restrict__ csr,
                        const float* __restrict__ as2, const float* __restrict__ ad2,
                        float* __restrict__ w2buf, float* __restrict__ den2){
  const int n = blockIdx.x*4 + (threadIdx.x >> 6);
  const int lane = threadIdx.x & 63;
  const int beg = offsets[n], end = offsets[n+1];
  const float ad = ad2[n];
  float d0 = 0.f;
  for(int i = beg + lane; i < end; i += 64){
    int s = clampi(csr[i], 0, N_NODES-1);
    float e = as2[s] + ad; e = (e>0.f)?e:0.2f*e;
    float w = __expf(fminf(e, 60.f));
    w2buf[i] = w;
    d0 += w;
  }
  #pragma unroll
  for(int off=32; off; off>>=1) d0 += __shfl_xor(d0, off, 64);
  if(lane == 0) den2[n] = d0 + 1e-16f;
}

// ---------------- Layer 2 aggregate + bias + ELU + FC(64->1) ----------------------

__global__ __launch_bounds__(256) void k_agg2(const int* __restrict__ offsets, const int* __restrict__ csr,
                       const bf16* __restrict__ h2, const float* __restrict__ w2buf,
                       const float* __restrict__ den2, const float* __restrict__ canon,
                       void* __restrict__ outv, const int* __restrict__ flag){
  const int n = blockIdx.x*4 + (threadIdx.x >> 6);
  const int c = threadIdx.x & 63;
  const int beg = offsets[n], end = offsets[n+1];
  float acc = 0.f;
  int i = beg;
  for(; i + 1 < end; i += 2){
    int s0 = csr[i], s1 = csr[i+1];
    float w0 = w2buf[i], w1 = w2buf[i+1];
    float v0 = b2f(h2[(size_t)s0*64 + c]);
    float v1 = b2f(h2[(size_t)s1*64 + c]);
    acc += w0*v0 + w1*v1;
  }
  if(i < end){
    int s0 = csr[i];
    acc += w2buf[i] * b2f(h2[(size_t)s0*64 + c]);
  }
  float o = acc / den2[n] + canon[OFF_B2 + c];
  o = (o > 0.f) ? o : expm1f(o);
  float v = o * canon[OFF_FCW + c];
  #pragma unroll
  for(int off=32; off; off>>=1) v += __shfl_xor(v, off, 64);
  if(c == 0){
    float r = v + canon[OFF_FCB];
    if(flag[1]) ((float*)outv)[n] = r;
    else        ((bf16*)outv)[n] = __float2bfloat16(r);
  }
}

// ---------------- launch ----------------

extern "C" void kernel_launch(void* const* d_in, const int* in_sizes, int n_in,
                              void* d_out, int out_size, void* d_ws, size_t ws_size,
                              hipStream_t stream){
  (void)in_sizes; (void)n_in; (void)out_size;
  const int* ei = (const int*)d_in[1];

  char* w = (char*)d_ws;
  auto carve = [&](size_t bytes)->char*{ char* p = w; w += (bytes + 255) & ~(size_t)255; return p; };
  int*      deg     = (int*)     carve((size_t)N_NODES*4);
  int*      offsets = (int*)     carve((size_t)(N_NODES+1)*4);
  int*      cursor  = (int*)     carve((size_t)N_NODES*4);
  int*      flag    = (int*)     carve(256);
  int*      csr     = (int*)     carve((size_t)E_TOT*4);
  float*    canon   = (float*)   carve((size_t)N_CANON*4);
  uint16_t* W2b     = (uint16_t*)carve((size_t)16384*2);
  float*    as1     = (float*)   carve((size_t)N_NODES*4*4);
  float*    ad1     = (float*)   carve((size_t)N_NODES*4*4);
  float*    as2     = (float*)   carve((size_t)N_NODES*4);
  float*    ad2     = (float*)   carve((size_t)N_NODES*4);
  float*    w1buf   = (float*)   carve((size_t)E_TOT*4*4);   // w2buf aliases (dead after agg1)
  float*    den1    = (float*)   carve((size_t)N_NODES*4*4); // den2 aliases
  bf16*     h2      = (bf16*)    carve((size_t)N_NODES*64*2);
  bf16*     h1o     = (bf16*)    carve((size_t)N_NODES*256*2);
  float*    w2buf   = w1buf;
  float*    den2    = den1;
  size_t required = (size_t)(w - (char*)d_ws);
  if(ws_size < required) return;               // diagnostic: output stays 0 => finite absmax

  hipLaunchKernelGGL(k_init,     dim3(197), dim3(256), 0, stream, deg, ei, (const uint16_t*)d_in[0], flag);
  hipLaunchKernelGGL(k_convert,  dim3((N_CANON+255)/256), dim3(256), 0, stream,
                     d_in[0], d_in[2], d_in[3], d_in[4], d_in[5], d_in[6], d_in[7], d_in[8],
                     d_in[9], d_in[10], d_in[11], canon, flag);
  hipLaunchKernelGGL(k_w2bf,     dim3(64), dim3(256), 0, stream, canon, W2b);
  hipLaunchKernelGGL(k_hist,     dim3((N_EDGES+255)/256), dim3(256), 0, stream, ei, deg, flag);
  hipLaunchKernelGGL(k_scan,     dim3(1), dim3(1024), 0, stream, deg, offsets, cursor);
  hipLaunchKernelGGL(k_scatter,  dim3((E_TOT+255)/256), dim3(256), 0, stream, ei, cursor, csr, flag);
  hipLaunchKernelGGL(k_alpha1,   dim3((N_NODES+255)/256), dim3(256), 0, stream, canon, as1, ad1);
  hipLaunchKernelGGL(k_edgew1,   dim3(N_NODES/4), dim3(256), 0, stream, offsets, csr, as1, ad1, w1buf, den1);
  hipLaunchKernelGGL(k_agg1,     dim3(2048), dim3(256), 0, stream, offsets, csr, canon, w1buf, den1, h1o);
  hipLaunchKernelGGL(k_gemm2,    dim3(782), dim3(256), 0, stream, h1o, W2b, canon, h2, as2, ad2);
  hipLaunchKernelGGL(k_edgew2,   dim3(N_NODES/4), dim3(256), 0, stream, offsets, csr, as2, ad2, w2buf, den2);
  hipLaunchKernelGGL(k_agg2,     dim3(N_NODES/4), dim3(256), 0, stream, offsets, csr, h2, w2buf, den2, canon, d_out, flag);
}

// Round 8
// 355.582 us; speedup vs baseline: 1.9680x; 1.1643x over previous
//
#include <hip/hip_runtime.h>
#include <hip/hip_bf16.h>
#include <stdint.h>

#define N_NODES 50000
#define N_EDGES 800000
#define E_TOT   (N_EDGES + N_NODES)

// canonical fp32 buffer segment offsets (element counts)
#define OFF_X    0
#define OFF_W1   800000
#define OFF_AS1  804096
#define OFF_AD1  804352
#define OFF_B1   804608
#define OFF_W2   804864
#define OFF_AS2  821248
#define OFF_AD2  821312
#define OFF_B2   821376
#define OFF_FCW  821440
#define OFF_FCB  821504
#define N_CANON  821505

typedef __hip_bfloat16 bf16;
typedef __attribute__((ext_vector_type(8))) short short8;   // 8 bf16 = 4 VGPRs
typedef __attribute__((ext_vector_type(4))) float f32x4;

__device__ __forceinline__ float b2f(bf16 v){ return (float)v; }
__device__ __forceinline__ int clampi(int v, int lo, int hi){ return v < lo ? lo : (v > hi ? hi : v); }
__device__ __forceinline__ uint16_t f2bfbits(float f){
  union { float f; uint32_t u; } c; c.f = f;
  uint32_t r = c.u + 0x7fff + ((c.u >> 16) & 1);   // round-to-nearest-even
  return (uint16_t)(r >> 16);
}
__device__ __forceinline__ float bitsf(uint32_t u){
  union { uint32_t u; float f; } c; c.u = u; return c.f;
}

__device__ __forceinline__ int load_src(const int* ei, int i, int f){
  return f ? ei[2*(size_t)i] : ei[i];
}
__device__ __forceinline__ int load_dst(const int* ei, int i, int f){
  return f ? ei[2*((size_t)N_EDGES + i)] : ei[N_EDGES + i];
}

// ---------------- init: deg=1 everywhere + dtype probes (merged launch) ----------
__global__ void k_init(int* __restrict__ deg, const int* __restrict__ ei,
                       const uint16_t* __restrict__ xu, int* __restrict__ flag){
  if(blockIdx.x < 196){
    int i = blockIdx.x*256 + threadIdx.x;
    if(i < N_NODES) deg[i] = 1;            // self-loop pre-counted
    return;
  }
  const int l = threadIdx.x;
  if(l >= 64) return;
  int or_odd = ei[2*l + 1] | ei[2*(400000 + l) + 1];
  int hits = 0;
  for(int k = 0; k < 64; k++){
    int e = (xu[l*64 + k] >> 7) & 0xFF;
    hits += (e >= 200);
  }
  #pragma unroll
  for(int off=32; off; off>>=1){
    or_odd |= __shfl_xor(or_odd, off, 64);
    hits   += __shfl_xor(hits,   off, 64);
  }
  if(l == 0){
    flag[0] = (or_odd == 0) ? 1 : 0;   // int64 edge_index
    flag[1] = (hits > 16) ? 1 : 0;     // fp32 float inputs
  }
}

// ---------------- canonicalize float inputs to fp32 ----------------
__global__ void k_convert(const void* x, const void* W1, const void* as1w, const void* ad1w,
                          const void* b1, const void* W2, const void* as2w, const void* ad2w,
                          const void* b2, const void* fcw, const void* fcb,
                          float* __restrict__ canon, const int* __restrict__ flag){
  int i = blockIdx.x*256 + threadIdx.x;
  if(i >= N_CANON) return;
  const void* src; int off;
  if     (i < OFF_W1 ){ src = x;    off = i; }
  else if(i < OFF_AS1){ src = W1;   off = i - OFF_W1; }
  else if(i < OFF_AD1){ src = as1w; off = i - OFF_AS1; }
  else if(i < OFF_B1 ){ src = ad1w; off = i - OFF_AD1; }
  else if(i < OFF_W2 ){ src = b1;   off = i - OFF_B1; }
  else if(i < OFF_AS2){ src = W2;   off = i - OFF_W2; }
  else if(i < OFF_AD2){ src = as2w; off = i - OFF_AS2; }
  else if(i < OFF_B2 ){ src = ad2w; off = i - OFF_AD2; }
  else if(i < OFF_FCW){ src = b2;   off = i - OFF_B2; }
  else if(i < OFF_FCB){ src = fcw;  off = i - OFF_FCW; }
  else               { src = fcb;  off = 0; }
  float v = flag[1] ? ((const float*)src)[off] : b2f(((const bf16*)src)[off]);
  canon[i] = v;
}

// W2 as bf16 [64][256] row-major (exact bits when input was bf16)
__global__ void k_w2bf(const float* __restrict__ canon, uint16_t* __restrict__ W2b){
  int i = blockIdx.x*256 + threadIdx.x;
  if(i < 16384) W2b[i] = f2bfbits(canon[OFF_W2 + i]);
}

// ---------------- CSR build ----------------

__global__ void k_hist(const int* __restrict__ ei, int* __restrict__ deg, const int* __restrict__ flag){
  int i = blockIdx.x*256 + threadIdx.x;
  if(i < N_EDGES){
    int d = clampi(load_dst(ei, i, flag[0]), 0, N_NODES-1);
    atomicAdd(&deg[d], 1);
  }
}

__global__ __launch_bounds__(1024) void k_scan(const int* deg, int* offsets, int* cursor){
  __shared__ int wsum[16];
  __shared__ int carry_s;
  const int tid = threadIdx.x, lane = tid & 63, wid = tid >> 6;
  if(tid == 0) carry_s = 0;
  __syncthreads();
  for(int base = 0; base < N_NODES; base += 4096){
    int i0 = base + tid*4;
    int v0 = (i0+0 < N_NODES) ? deg[i0+0] : 0;
    int v1 = (i0+1 < N_NODES) ? deg[i0+1] : 0;
    int v2 = (i0+2 < N_NODES) ? deg[i0+2] : 0;
    int v3 = (i0+3 < N_NODES) ? deg[i0+3] : 0;
    int s = v0+v1+v2+v3;
    int incl = s;
    #pragma unroll
    for(int off=1; off<64; off<<=1){
      int t = __shfl_up(incl, off, 64);
      if(lane >= off) incl += t;
    }
    if(lane == 63) wsum[wid] = incl;
    __syncthreads();
    int wexcl = 0, total = 0;
    #pragma unroll
    for(int w=0; w<16; w++){
      int ws_ = wsum[w];
      if(w < wid) wexcl += ws_;
      total += ws_;
    }
    int o = carry_s + wexcl + (incl - s);
    if(i0+0 < N_NODES){ offsets[i0+0]=o; cursor[i0+0]=o; } o += v0;
    if(i0+1 < N_NODES){ offsets[i0+1]=o; cursor[i0+1]=o; } o += v1;
    if(i0+2 < N_NODES){ offsets[i0+2]=o; cursor[i0+2]=o; } o += v2;
    if(i0+3 < N_NODES){ offsets[i0+3]=o; cursor[i0+3]=o; }
    __syncthreads();
    if(tid == 0) carry_s += total;
    __syncthreads();
  }
  if(tid == 0) offsets[N_NODES] = carry_s;   // == E_TOT
}

__global__ void k_scatter(const int* __restrict__ ei, int* __restrict__ cursor, int* __restrict__ csr,
                          const int* __restrict__ flag){
  int i = blockIdx.x*256 + threadIdx.x;
  if(i >= E_TOT) return;
  int s, d;
  if(i < N_EDGES){
    int f = flag[0];
    s = clampi(load_src(ei, i, f), 0, N_NODES-1);
    d = clampi(load_dst(ei, i, f), 0, N_NODES-1);
  } else {
    s = i - N_EDGES; d = s;
  }
  int pos = atomicAdd(&cursor[d], 1);
  pos = clampi(pos, 0, E_TOT-1);
  csr[pos] = s;
}

// ---------------- Layer 1 alpha: as1/ad1 = X @ p^T via folded attention ----------
// p_src[h,k] = sum_c a_src[h,c]*W1[h*64+c,k]  (exact linear fold; no h1 needed)

__global__ __launch_bounds__(256) void k_alpha1(const float* __restrict__ canon,
                        float* __restrict__ as1, float* __restrict__ ad1){
  __shared__ float ps[64], pd[64];
  const int tid = threadIdx.x;
  if(tid < 128){
    int e = tid & 63;                    // h*16+k
    int h = e >> 4, k = e & 15;
    const float* av = canon + (tid < 64 ? OFF_AS1 : OFF_AD1) + h*64;
    const float* Wp = canon + OFF_W1 + (h*64)*16 + k;
    float acc = 0.f;
    #pragma unroll 8
    for(int c = 0; c < 64; c++) acc += av[c] * Wp[c*16];
    (tid < 64 ? ps : pd)[e] = acc;
  }
  __syncthreads();
  int n = blockIdx.x*256 + tid;
  if(n >= N_NODES) return;
  float xr[16];
  const float4* xp = (const float4*)(canon + OFF_X + n*16);
  #pragma unroll
  for(int t=0;t<4;t++){ float4 v = xp[t]; xr[4*t]=v.x; xr[4*t+1]=v.y; xr[4*t+2]=v.z; xr[4*t+3]=v.w; }
  float s[4], d[4];
  #pragma unroll
  for(int h=0;h<4;h++){
    float a=0.f, b=0.f;
    #pragma unroll
    for(int k=0;k<16;k++){ a += ps[h*16+k]*xr[k]; b += pd[h*16+k]*xr[k]; }
    s[h]=a; d[h]=b;
  }
  ((float4*)as1)[n] = make_float4(s[0],s[1],s[2],s[3]);
  ((float4*)ad1)[n] = make_float4(d[0],d[1],d[2],d[3]);
}

// ---------------- Layer 1: fused softmax-weights + aggregate(raw x) + W1 + ELU ----
// wave per node; lane = (h = lane>>4, k = lane&15). Single pass:
//   den = sum_s w_s ; y[h][k] = sum_s w_s * x[s][k]   (w computed inline per lane)
// epilogue: shfl all-gather of y within head group, o = ELU(W1·(y/den) + b1).

__global__ __launch_bounds__(256) void k_agg1(const int* __restrict__ offsets, const int* __restrict__ csr,
                       const float* __restrict__ canon, const float* __restrict__ as1,
                       const float* __restrict__ ad1, bf16* __restrict__ h1o){
  const int wv = threadIdx.x >> 6, lane = threadIdx.x & 63;
  const int h = lane >> 4;

  float w1f[64];                                   // W1 rows lane*4..lane*4+3
  const float4* wsrc = (const float4*)(canon + OFF_W1 + lane*64);
  #pragma unroll
  for(int t=0;t<16;t++){
    float4 v = wsrc[t];
    w1f[4*t]=v.x; w1f[4*t+1]=v.y; w1f[4*t+2]=v.z; w1f[4*t+3]=v.w;
  }
  float4 bb = ((const float4*)(canon + OFF_B1))[lane];
  const float* xf = canon + OFF_X;
  const int k = lane & 15;

  for(int n = blockIdx.x*4 + wv; n < N_NODES; n += gridDim.x*4){
    const int beg = offsets[n], end = offsets[n+1];
    const float adh = ad1[n*4 + h];
    float y = 0.f, den = 0.f;
    for(int i0 = beg; i0 < end; i0 += 8){
      int idx[8]; float av[8], xv[8]; bool val[8];
      #pragma unroll
      for(int j=0;j<8;j++){
        int i = i0 + j;
        val[j] = (i < end);
        idx[j] = csr[val[j] ? i : beg];
      }
      #pragma unroll
      for(int j=0;j<8;j++) av[j] = as1[idx[j]*4 + h];
      #pragma unroll
      for(int j=0;j<8;j++) xv[j] = xf[idx[j]*16 + k];
      #pragma unroll
      for(int j=0;j<8;j++){
        float e = av[j] + adh;
        e = (e > 0.f) ? e : 0.2f*e;
        float w = __expf(fminf(e, 60.f));
        w = val[j] ? w : 0.f;
        den += w;
        y += w * xv[j];
      }
    }
    y *= 1.f / (den + 1e-16f);
    // all-gather y across the 16 lanes of this head group, apply W1 fragment
    float o0=bb.x, o1=bb.y, o2=bb.z, o3=bb.w;
    const int base = lane & 48;
    #pragma unroll
    for(int j=0;j<16;j++){
      float yj = __shfl(y, base | j, 64);
      o0 += w1f[j]      * yj;
      o1 += w1f[16 + j] * yj;
      o2 += w1f[32 + j] * yj;
      o3 += w1f[48 + j] * yj;
    }
    o0 = (o0>0.f)?o0:expm1f(o0); o1 = (o1>0.f)?o1:expm1f(o1);
    o2 = (o2>0.f)?o2:expm1f(o2); o3 = (o3>0.f)?o3:expm1f(o3);
    uint2 r;
    r.x = (uint32_t)f2bfbits(o0) | ((uint32_t)f2bfbits(o1) << 16);
    r.y = (uint32_t)f2bfbits(o2) | ((uint32_t)f2bfbits(o3) << 16);
    *(uint2*)(h1o + (size_t)n*256 + lane*4) = r;
  }
}

// ---------------- Layer 2 GEMM via MFMA: [50000x256]x[256x64], fused alpha2 -------

__global__ __launch_bounds__(256) void k_gemm2(const bf16* __restrict__ h1o, const uint16_t* __restrict__ W2b,
                        const float* __restrict__ canon,
                        bf16* __restrict__ h2, float* __restrict__ as2, float* __restrict__ ad2){
  const int tid = threadIdx.x, lane = tid & 63, wave = tid >> 6;
  const int quad = lane >> 4, c = lane & 15;

  short8 bfrag[4][8];
  #pragma unroll
  for(int cb=0; cb<4; cb++)
    #pragma unroll
    for(int ks=0; ks<8; ks++)
      bfrag[cb][ks] = *(const short8*)(W2b + (cb*16 + c)*256 + ks*32 + quad*8);

  float asj[4], adj[4];
  #pragma unroll
  for(int cb=0; cb<4; cb++){
    asj[cb] = canon[OFF_AS2 + cb*16 + c];
    adj[cb] = canon[OFF_AD2 + cb*16 + c];
  }

  const int tiles = N_NODES/16;                 // 3125
  const int gw = blockIdx.x*4 + wave, nw = gridDim.x*4;
  for(int t = gw; t < tiles; t += nw){
    const int n0 = t*16;
    f32x4 acc[4];
    #pragma unroll
    for(int cb=0; cb<4; cb++) acc[cb] = (f32x4){0.f,0.f,0.f,0.f};

    const bf16* arow = h1o + (size_t)(n0 + c)*256 + quad*8;
    #pragma unroll
    for(int ks=0; ks<8; ks++){
      short8 af = *(const short8*)(arow + ks*32);
      acc[0] = __builtin_amdgcn_mfma_f32_16x16x32_bf16(af, bfrag[0][ks], acc[0], 0,0,0);
      acc[1] = __builtin_amdgcn_mfma_f32_16x16x32_bf16(af, bfrag[1][ks], acc[1], 0,0,0);
      acc[2] = __builtin_amdgcn_mfma_f32_16x16x32_bf16(af, bfrag[2][ks], acc[2], 0,0,0);
      acc[3] = __builtin_amdgcn_mfma_f32_16x16x32_bf16(af, bfrag[3][ks], acc[3], 0,0,0);
    }

    float vs[4] = {0.f,0.f,0.f,0.f}, vd[4] = {0.f,0.f,0.f,0.f};
    #pragma unroll
    for(int cb=0; cb<4; cb++)
      #pragma unroll
      for(int r=0; r<4; r++){
        float v = acc[cb][r];
        h2[(size_t)(n0 + quad*4 + r)*64 + cb*16 + c] = __float2bfloat16(v);
        vs[r] += v * asj[cb];
        vd[r] += v * adj[cb];
      }
    #pragma unroll
    for(int r=0; r<4; r++){
      #pragma unroll
      for(int off=1; off<16; off<<=1){
        vs[r] += __shfl_xor(vs[r], off, 64);
        vd[r] += __shfl_xor(vd[r], off, 64);
      }
    }
    if(c == 0){
      #pragma unroll
      for(int r=0; r<4; r++){
        as2[n0 + quad*4 + r] = vs[r];
        ad2[n0 + quad*4 + r] = vd[r];
      }
    }
  }
}

// ---------------- Layer 2: fused softmax-weights + aggregate + bias+ELU+FC --------
// wave per node; lane = channel c. w computed inline (redundant across lanes).

__global__ __launch_bounds__(256) void k_agg2(const int* __restrict__ offsets, const int* __restrict__ csr,
                       const bf16* __restrict__ h2, const float* __restrict__ as2,
                       const float* __restrict__ ad2, const float* __restrict__ canon,
                       void* __restrict__ outv, const int* __restrict__ flag){
  const int wv = threadIdx.x >> 6, c = threadIdx.x & 63;
  const uint16_t* h2u = (const uint16_t*)h2;
  for(int n = blockIdx.x*4 + wv; n < N_NODES; n += gridDim.x*4){
    const int beg = offsets[n], end = offsets[n+1];
    const float adn = ad2[n];
    float acc = 0.f, den = 0.f;
    for(int i0 = beg; i0 < end; i0 += 8){
      int idx[8]; float av[8]; uint16_t hv[8]; bool val[8];
      #pragma unroll
      for(int j=0;j<8;j++){
        int i = i0 + j;
        val[j] = (i < end);
        idx[j] = csr[val[j] ? i : beg];
      }
      #pragma unroll
      for(int j=0;j<8;j++) av[j] = as2[idx[j]];
      #pragma unroll
      for(int j=0;j<8;j++) hv[j] = h2u[(size_t)idx[j]*64 + c];
      #pragma unroll
      for(int j=0;j<8;j++){
        float e = av[j] + adn;
        e = (e > 0.f) ? e : 0.2f*e;
        float w = __expf(fminf(e, 60.f));
        w = val[j] ? w : 0.f;
        den += w;
        acc += w * bitsf((uint32_t)hv[j] << 16);
      }
    }
    float o = acc/(den + 1e-16f) + canon[OFF_B2 + c];
    o = (o > 0.f) ? o : expm1f(o);
    float v = o * canon[OFF_FCW + c];
    #pragma unroll
    for(int off=32; off; off>>=1) v += __shfl_xor(v, off, 64);
    if(c == 0){
      float r = v + canon[OFF_FCB];
      if(flag[1]) ((float*)outv)[n] = r;
      else        ((bf16*)outv)[n] = __float2bfloat16(r);
    }
  }
}

// ---------------- launch ----------------

extern "C" void kernel_launch(void* const* d_in, const int* in_sizes, int n_in,
                              void* d_out, int out_size, void* d_ws, size_t ws_size,
                              hipStream_t stream){
  (void)in_sizes; (void)n_in; (void)out_size;
  const int* ei = (const int*)d_in[1];

  char* w = (char*)d_ws;
  auto carve = [&](size_t bytes)->char*{ char* p = w; w += (bytes + 255) & ~(size_t)255; return p; };
  int*      deg     = (int*)     carve((size_t)N_NODES*4);
  int*      offsets = (int*)     carve((size_t)(N_NODES+1)*4);
  int*      cursor  = (int*)     carve((size_t)N_NODES*4);
  int*      flag    = (int*)     carve(256);
  int*      csr     = (int*)     carve((size_t)E_TOT*4);
  float*    canon   = (float*)   carve((size_t)N_CANON*4);
  uint16_t* W2b     = (uint16_t*)carve((size_t)16384*2);
  float*    as1     = (float*)   carve((size_t)N_NODES*4*4);
  float*    ad1     = (float*)   carve((size_t)N_NODES*4*4);
  float*    as2     = (float*)   carve((size_t)N_NODES*4);
  float*    ad2     = (float*)   carve((size_t)N_NODES*4);
  bf16*     h2      = (bf16*)    carve((size_t)N_NODES*64*2);
  bf16*     h1o     = (bf16*)    carve((size_t)N_NODES*256*2);
  size_t required = (size_t)(w - (char*)d_ws);
  if(ws_size < required) return;               // diagnostic: output stays 0 => finite absmax

  hipLaunchKernelGGL(k_init,     dim3(197), dim3(256), 0, stream, deg, ei, (const uint16_t*)d_in[0], flag);
  hipLaunchKernelGGL(k_convert,  dim3((N_CANON+255)/256), dim3(256), 0, stream,
                     d_in[0], d_in[2], d_in[3], d_in[4], d_in[5], d_in[6], d_in[7], d_in[8],
                     d_in[9], d_in[10], d_in[11], canon, flag);
  hipLaunchKernelGGL(k_w2bf,     dim3(64), dim3(256), 0, stream, canon, W2b);
  hipLaunchKernelGGL(k_hist,     dim3((N_EDGES+255)/256), dim3(256), 0, stream, ei, deg, flag);
  hipLaunchKernelGGL(k_scan,     dim3(1), dim3(1024), 0, stream, deg, offsets, cursor);
  hipLaunchKernelGGL(k_scatter,  dim3((E_TOT+255)/256), dim3(256), 0, stream, ei, cursor, csr, flag);
  hipLaunchKernelGGL(k_alpha1,   dim3((N_NODES+255)/256), dim3(256), 0, stream, canon, as1, ad1);
  hipLaunchKernelGGL(k_agg1,     dim3(2048), dim3(256), 0, stream, offsets, csr, canon, as1, ad1, h1o);
  hipLaunchKernelGGL(k_gemm2,    dim3(782), dim3(256), 0, stream, h1o, W2b, canon, h2, as2, ad2);
  hipLaunchKernelGGL(k_agg2,     dim3(N_NODES/4), dim3(256), 0, stream, offsets, csr, h2, as2, ad2, canon, d_out, flag);
}